// Round 8
// baseline (199.631 us; speedup 1.0000x reference)
//
#include <hip/hip_runtime.h>
#include <hip/hip_fp8.h>

#define N_NODES 50000
#define N_EDGES 800000
#define NBUCK 196       // ceil(50000/256) buckets of 256 nodes
#define PBLK 391        // ceil(800000/2048) partition blocks
#define PREPBLK 1980    // prep section blocks
#define CAP 5120        // bucket window capacity

typedef unsigned short ushort_t;
typedef unsigned char uchar_t;
typedef short short8 __attribute__((ext_vector_type(8)));
typedef short short4v __attribute__((ext_vector_type(4)));
typedef float floatx4 __attribute__((ext_vector_type(4)));
typedef float floatx2 __attribute__((ext_vector_type(2)));

__device__ __forceinline__ float bf2f(ushort_t u) {
    unsigned v = ((unsigned)u) << 16;
    return __builtin_bit_cast(float, v);
}
__device__ __forceinline__ ushort_t f2bf(float f) {
    unsigned u = __builtin_bit_cast(unsigned, f);
    unsigned r = (u + 0x7FFFu + ((u >> 16) & 1u)) >> 16;  // RNE
    return (ushort_t)r;
}
// HW OCP fp8 converts (gfx950)
__device__ __forceinline__ uchar_t f2fp8(float f) {
    return (uchar_t)(__builtin_amdgcn_cvt_pk_fp8_f32(f, f, 0, false) & 0xFF);
}
__device__ __forceinline__ float4 ld4(const float* p) { return *(const float4*)p; }

__device__ __forceinline__ void acc16(float* a, uint4 v) {
    unsigned ws[4] = {v.x, v.y, v.z, v.w};
    #pragma unroll
    for (int wi = 0; wi < 4; ++wi) {
        floatx2 lo = __builtin_amdgcn_cvt_pk_f32_fp8(ws[wi], false);
        floatx2 hi = __builtin_amdgcn_cvt_pk_f32_fp8(ws[wi], true);
        a[wi * 4 + 0] += lo.x; a[wi * 4 + 1] += lo.y;
        a[wi * 4 + 2] += hi.x; a[wi * 4 + 3] += hi.y;
    }
}
__device__ __forceinline__ void acc8(float* a, uint2 v) {
    floatx2 p0 = __builtin_amdgcn_cvt_pk_f32_fp8(v.x, false);
    floatx2 p1 = __builtin_amdgcn_cvt_pk_f32_fp8(v.x, true);
    floatx2 p2 = __builtin_amdgcn_cvt_pk_f32_fp8(v.y, false);
    floatx2 p3 = __builtin_amdgcn_cvt_pk_f32_fp8(v.y, true);
    a[0] += p0.x; a[1] += p0.y; a[2] += p1.x; a[3] += p1.y;
    a[4] += p2.x; a[5] += p2.y; a[6] += p3.x; a[7] += p3.y;
}

// ---------------- merged prep + partition ----------------
// blocks [0, PREPBLK)         : cvt_x (bf16+fp8) + transposed weights
// blocks [PREPBLK, +PBLK)     : single-pass partition into bucket windows
//                               (bcursor is RELATIVE count, memset-zeroed)
__global__ __launch_bounds__(256) void prep_part_kernel(
    const float* __restrict__ x,
    const float* __restrict__ W1_rel, const float* __restrict__ W1_root,
    const float* __restrict__ W2_rel, const float* __restrict__ W2_root,
    const float* __restrict__ Wmu_rel, const float* __restrict__ Wls_rel,
    const float* __restrict__ Wmu_root, const float* __restrict__ Wls_root,
    const int* __restrict__ src, const int* __restrict__ dst,
    ushort_t* __restrict__ xb, uchar_t* __restrict__ xq,
    ushort_t* __restrict__ B1t, ushort_t* __restrict__ B2t, ushort_t* __restrict__ B3t,
    int* __restrict__ bcursor, unsigned* __restrict__ pairbuf) {
    __shared__ int h[NBUCK];
    __shared__ int cur[NBUCK];
    const int tid = threadIdx.x;
    if (blockIdx.x < PREPBLK) {
        int idx = blockIdx.x * 256 + tid;
        if (idx < 400000) {                       // xb[n,:] = bf16(x); xq[n,:] = fp8(x)
            int n = idx >> 3, c = (idx & 7) * 8;
            float4 v0 = ld4(x + (size_t)n * 64 + c);
            float4 v1 = ld4(x + (size_t)n * 64 + c + 4);
            float vv[8] = {v0.x, v0.y, v0.z, v0.w, v1.x, v1.y, v1.z, v1.w};
            short8 o;
            #pragma unroll
            for (int i = 0; i < 8; ++i) o[i] = f2bf(vv[i]);
            int q0 = __builtin_amdgcn_cvt_pk_fp8_f32(vv[0], vv[1], 0, false);
            q0 = __builtin_amdgcn_cvt_pk_fp8_f32(vv[2], vv[3], q0, true);
            int q1 = __builtin_amdgcn_cvt_pk_fp8_f32(vv[4], vv[5], 0, false);
            q1 = __builtin_amdgcn_cvt_pk_fp8_f32(vv[6], vv[7], q1, true);
            *(short8*)(xb + (size_t)n * 64 + c) = o;
            uint2 q = {(unsigned)q0, (unsigned)q1};
            *(uint2*)(xq + (size_t)n * 64 + c) = q;
        } else if (idx < 506496) {                // transposed bf16 weights
            int j = idx - 400000;
            if (j < 32768) {
                int n = j >> 7, k = j & 127;
                float v = (k < 64) ? W1_rel[k * 256 + n] : W1_root[(k - 64) * 256 + n];
                B1t[j] = f2bf(v);
            } else if (j < 98304) {
                int jj = j - 32768;
                int n = jj >> 8, k = jj & 255;
                float v = (n < 128) ? W2_rel[k * 128 + n] : W2_root[k * 128 + (n - 128)];
                B2t[jj] = f2bf(v);
            } else {
                int jj = j - 98304;
                int n = jj >> 7, k = jj & 127;
                const float* W = (n < 16) ? Wmu_rel : (n < 32) ? Wls_rel : (n < 48) ? Wmu_root : Wls_root;
                B3t[jj] = f2bf(W[k * 16 + (n & 15)]);
            }
        }
        return;
    }
    // ---- partition section ----
    const int pb = blockIdx.x - PREPBLK;
    for (int i = tid; i < NBUCK; i += 256) h[i] = 0;
    __syncthreads();
    const int base = pb * 2048;
    int d[8];
    #pragma unroll
    for (int j = 0; j < 8; ++j) {
        int e = base + j * 256 + tid;
        if (e < N_EDGES) { d[j] = dst[e]; atomicAdd(&h[d[j] >> 8], 1); }
        else d[j] = -1;
    }
    __syncthreads();
    for (int i = tid; i < NBUCK; i += 256) {
        int c = h[i];
        cur[i] = c ? (i * CAP + atomicAdd(&bcursor[i], c)) : 0;
    }
    __syncthreads();
    #pragma unroll
    for (int j = 0; j < 8; ++j) {
        int e = base + j * 256 + tid;
        if (e < N_EDGES) {
            int dd = d[j];
            int slot = atomicAdd(&cur[dd >> 8], 1);
            pairbuf[slot] = (unsigned)src[e] | ((unsigned)(dd & 255) << 16);
        }
    }
}

// per-bucket (1024 thr): node histogram + scan -> row_beg/row_end/dinv; LDS-cursor eidx fill
__global__ __launch_bounds__(1024) void fill_bucket_kernel(
    const unsigned* __restrict__ pairbuf, const int* __restrict__ bcursor,
    int* __restrict__ row_beg, int* __restrict__ row_end,
    float* __restrict__ dinv, ushort_t* __restrict__ eidx) {
    __shared__ int h[256];
    __shared__ int sm[256];
    __shared__ int cur[256];
    const int b = blockIdx.x, tid = threadIdx.x;
    const int beg = b * CAP, end = beg + bcursor[b];
    if (tid < 256) h[tid] = 0;
    __syncthreads();
    for (int i = beg + tid; i < end; i += 1024)
        atomicAdd(&h[pairbuf[i] >> 16], 1);
    __syncthreads();
    if (tid < 256) sm[tid] = h[tid];
    __syncthreads();
    #pragma unroll
    for (int off = 1; off < 256; off <<= 1) {
        int t = 0;
        if (tid < 256 && tid >= off) t = sm[tid - off];
        __syncthreads();
        if (tid < 256) sm[tid] += t;
        __syncthreads();
    }
    if (tid < 256) {
        int c = h[tid];
        int exc = beg + sm[tid] - c;
        int node = b * 256 + tid;
        if (node < N_NODES) {
            row_beg[node] = exc;
            row_end[node] = exc + c;
            dinv[node] = c > 0 ? 1.0f / (float)c : 0.0f;
        }
        cur[tid] = exc;
    }
    __syncthreads();
    for (int i = beg + tid; i < end; i += 1024) {
        unsigned v = pairbuf[i];
        int slot = atomicAdd(&cur[v >> 16], 1);
        eidx[slot] = (ushort_t)(v & 0xFFFFu);
    }
}

// ---------------- fused gather1 + gemm1 + gemm2 (50 KB LDS -> 3 blocks/CU) ----------------
__global__ __launch_bounds__(256, 3) void g1gemm12(
    const ushort_t* __restrict__ xb, const uchar_t* __restrict__ xq,
    const int* __restrict__ row_beg, const int* __restrict__ row_end,
    const ushort_t* __restrict__ eidx, const float* __restrict__ dinv,
    const ushort_t* __restrict__ B1t, const float* __restrict__ b1,
    const ushort_t* __restrict__ B2t,
    uchar_t* __restrict__ t2, ushort_t* __restrict__ r2) {
    constexpr int K1 = 128, K2 = 256;
    constexpr int AKP = 72;    // agg tile pitch (64+8)
    constexpr int HKP = 264;   // h1 tile pitch (256+8)
    constexpr int BKP = 136;   // B strip pitch (128+8)
    __shared__ ushort_t Bs[64 * BKP];   // 17.4 KB (As aliased during phase 0)
    __shared__ ushort_t Hs[64 * HKP];   // 33.8 KB (out-tiles aliased after a2 consumed)
    ushort_t* As = Bs;
    const int tid = threadIdx.x;
    const int rowbase = blockIdx.x * 64;

    // ---- phase 0: gather mean of fp8 neighbor rows (8 loads in flight) ----
    {
        const int nl = tid >> 2, lane = tid & 3;   // 4 lanes/node, 16 fp8 each
        const int node = rowbase + nl;
        int beg = 0, end = 0;
        float d = 0.0f;
        if (node < N_NODES) { beg = row_beg[node]; end = row_end[node]; d = dinv[node]; }
        float a0[16] = {}, a1[16] = {};
        int j = beg;
        for (; j + 7 < end; j += 8) {
            uint4 v0 = *(const uint4*)(xq + (size_t)eidx[j] * 64 + lane * 16);
            uint4 v1 = *(const uint4*)(xq + (size_t)eidx[j + 1] * 64 + lane * 16);
            uint4 v2 = *(const uint4*)(xq + (size_t)eidx[j + 2] * 64 + lane * 16);
            uint4 v3 = *(const uint4*)(xq + (size_t)eidx[j + 3] * 64 + lane * 16);
            uint4 v4 = *(const uint4*)(xq + (size_t)eidx[j + 4] * 64 + lane * 16);
            uint4 v5 = *(const uint4*)(xq + (size_t)eidx[j + 5] * 64 + lane * 16);
            uint4 v6 = *(const uint4*)(xq + (size_t)eidx[j + 6] * 64 + lane * 16);
            uint4 v7 = *(const uint4*)(xq + (size_t)eidx[j + 7] * 64 + lane * 16);
            acc16(a0, v0); acc16(a1, v1); acc16(a0, v2); acc16(a1, v3);
            acc16(a0, v4); acc16(a1, v5); acc16(a0, v6); acc16(a1, v7);
        }
        for (; j + 3 < end; j += 4) {
            uint4 v0 = *(const uint4*)(xq + (size_t)eidx[j] * 64 + lane * 16);
            uint4 v1 = *(const uint4*)(xq + (size_t)eidx[j + 1] * 64 + lane * 16);
            uint4 v2 = *(const uint4*)(xq + (size_t)eidx[j + 2] * 64 + lane * 16);
            uint4 v3 = *(const uint4*)(xq + (size_t)eidx[j + 3] * 64 + lane * 16);
            acc16(a0, v0); acc16(a1, v1); acc16(a0, v2); acc16(a1, v3);
        }
        for (; j < end; ++j) {
            uint4 v0 = *(const uint4*)(xq + (size_t)eidx[j] * 64 + lane * 16);
            acc16(a0, v0);
        }
        short8 o0, o1;
        #pragma unroll
        for (int i = 0; i < 8; ++i) {
            o0[i] = f2bf((a0[i] + a1[i]) * d);
            o1[i] = f2bf((a0[8 + i] + a1[8 + i]) * d);
        }
        *(short8*)(As + nl * AKP + lane * 16) = o0;
        *(short8*)(As + nl * AKP + lane * 16 + 8) = o1;
    }
    __syncthreads();

    const int w = tid >> 6, lane64 = tid & 63;
    const int ln = lane64 & 15, quad = lane64 >> 4;
    const int rwl = w * 16 + ln;
    int r = rowbase + rwl;
    if (r > N_NODES - 1) r = N_NODES - 1;

    float bias[4][4];
    #pragma unroll
    for (int ny = 0; ny < 4; ++ny)
        #pragma unroll
        for (int f = 0; f < 4; ++f)
            bias[ny][f] = b1[ny * 64 + f * 16 + ln];

    // ---- phase 1: gemm1, A = [As | xb], B staged with reg-prefetch ----
    short8 a[4];
    a[0] = *(const short8*)(As + rwl * AKP + quad * 8);
    a[1] = *(const short8*)(As + rwl * AKP + 32 + quad * 8);
    a[2] = *(const short8*)(xb + (size_t)r * 64 + quad * 8);
    a[3] = *(const short8*)(xb + (size_t)r * 64 + 32 + quad * 8);
    {
        short8 pb[4];
        #pragma unroll
        for (int i = 0; i < 4; ++i) {
            int idx = tid + i * 256, row = idx >> 4, off = (idx & 15) * 8;
            pb[i] = *(const short8*)(B1t + (size_t)row * K1 + off);
        }
        for (int ny = 0; ny < 4; ++ny) {
            __syncthreads();
            #pragma unroll
            for (int i = 0; i < 4; ++i) {
                int idx = tid + i * 256, row = idx >> 4, off = (idx & 15) * 8;
                *(short8*)(Bs + row * BKP + off) = pb[i];
            }
            if (ny < 3) {
                #pragma unroll
                for (int i = 0; i < 4; ++i) {
                    int idx = tid + i * 256, row = idx >> 4, off = (idx & 15) * 8;
                    pb[i] = *(const short8*)(B1t + (size_t)((ny + 1) * 64 + row) * K1 + off);
                }
            }
            __syncthreads();
            floatx4 acc[4] = {};
            #pragma unroll
            for (int f = 0; f < 4; ++f) {
                const ushort_t* bp = Bs + (f * 16 + ln) * BKP + quad * 8;
                #pragma unroll
                for (int s = 0; s < 4; ++s) {
                    short8 b = *(const short8*)(bp + s * 32);
                    acc[f] = __builtin_amdgcn_mfma_f32_16x16x32_bf16(a[s], b, acc[f], 0, 0, 0);
                }
            }
            #pragma unroll
            for (int f = 0; f < 4; ++f) {
                int n = ny * 64 + f * 16 + ln;
                #pragma unroll
                for (int g = 0; g < 4; ++g) {
                    int rr = w * 16 + quad * 4 + g;
                    Hs[rr * HKP + n] = f2bf(fmaxf(acc[f][g] + bias[ny][f], 0.0f));
                }
            }
        }
    }
    __syncthreads();

    // ---- phase 2: gemm2, A = Hs (to regs; Hs region becomes output tiles) ----
    short8 a2[8];
    #pragma unroll
    for (int s = 0; s < 8; ++s)
        a2[s] = *(const short8*)(Hs + rwl * HKP + s * 32 + quad * 8);
    ushort_t* Or16 = Hs;                          // pitch 136 ush (bf16 tile)
    uchar_t*  Ot8  = (uchar_t*)(Hs + 8704);       // pitch 144 B (fp8 tile)
    {
        short8 pb[4];
        #pragma unroll
        for (int i = 0; i < 4; ++i) {
            int idx = tid + i * 256, row = idx >> 4, off = (idx & 15) * 8;
            pb[i] = *(const short8*)(B2t + (size_t)row * K2 + off);
        }
        for (int ny = 0; ny < 4; ++ny) {
            floatx4 acc[4] = {};
            #pragma unroll
            for (int kh = 0; kh < 2; ++kh) {
                __syncthreads();
                #pragma unroll
                for (int i = 0; i < 4; ++i) {
                    int idx = tid + i * 256, row = idx >> 4, off = (idx & 15) * 8;
                    *(short8*)(Bs + row * BKP + off) = pb[i];
                }
                int st = ny * 2 + kh;
                if (st < 7) {
                    int nyn = (st + 1) >> 1, khn = (st + 1) & 1;
                    #pragma unroll
                    for (int i = 0; i < 4; ++i) {
                        int idx = tid + i * 256, row = idx >> 4, off = (idx & 15) * 8;
                        pb[i] = *(const short8*)(B2t + (size_t)(nyn * 64 + row) * K2 + khn * 128 + off);
                    }
                }
                __syncthreads();
                #pragma unroll
                for (int f = 0; f < 4; ++f) {
                    const ushort_t* bp = Bs + (f * 16 + ln) * BKP + quad * 8;
                    #pragma unroll
                    for (int s = 0; s < 4; ++s) {
                        short8 b = *(const short8*)(bp + s * 32);
                        acc[f] = __builtin_amdgcn_mfma_f32_16x16x32_bf16(a2[kh * 4 + s], b, acc[f], 0, 0, 0);
                    }
                }
            }
            #pragma unroll
            for (int f = 0; f < 4; ++f) {
                int n = ny * 64 + f * 16 + ln;
                #pragma unroll
                for (int g = 0; g < 4; ++g) {
                    int rr = w * 16 + quad * 4 + g;
                    float v = acc[f][g];
                    if (n < 128) Ot8[rr * 144 + n] = f2fp8(v);
                    else Or16[rr * 136 + (n - 128)] = f2bf(v);
                }
            }
        }
    }
    __syncthreads();

    // ---- coalesced store-out of both tiles ----
    {
        const int row = tid >> 2, seg = tid & 3;
        const int gr = rowbase + row;
        if (gr < N_NODES) {
            const uint4* ps = (const uint4*)(Ot8 + row * 144 + seg * 32);
            uint4* pd = (uint4*)(t2 + (size_t)gr * 128 + seg * 32);
            pd[0] = ps[0]; pd[1] = ps[1];
            const uint4* qs = (const uint4*)(Or16 + row * 136 + seg * 32);
            uint4* qd = (uint4*)(r2 + (size_t)gr * 128 + seg * 32);
            qd[0] = qs[0]; qd[1] = qs[1]; qd[2] = qs[2]; qd[3] = qs[3];
        }
    }
}

// ---------------- fused gather2 + combine + gemm3 (16 nodes/block, 16 threads/node) ----------------
__global__ __launch_bounds__(256) void g2g3_kernel(
    const uchar_t* __restrict__ t2, const ushort_t* __restrict__ r2,
    const int* __restrict__ row_beg, const int* __restrict__ row_end,
    const ushort_t* __restrict__ eidx, const float* __restrict__ dinv,
    const float* __restrict__ b2, const ushort_t* __restrict__ B3t,
    ushort_t* __restrict__ tml, float* __restrict__ rml) {
    constexpr int KP = 136;
    __shared__ ushort_t As[16 * KP];
    const int tid = threadIdx.x;
    const int nb = blockIdx.x * 16;   // 3125*16 = 50000 exact
    {
        const int nl = tid >> 4, lane = tid & 15;
        const int node = nb + nl;
        const int beg = row_beg[node], end = row_end[node];
        float a0[8] = {}, a1[8] = {}, a2[8] = {}, a3[8] = {};
        int j = beg;
        for (; j + 7 < end; j += 8) {
            uint2 v0 = *(const uint2*)(t2 + (size_t)eidx[j] * 128 + lane * 8);
            uint2 v1 = *(const uint2*)(t2 + (size_t)eidx[j + 1] * 128 + lane * 8);
            uint2 v2 = *(const uint2*)(t2 + (size_t)eidx[j + 2] * 128 + lane * 8);
            uint2 v3 = *(const uint2*)(t2 + (size_t)eidx[j + 3] * 128 + lane * 8);
            uint2 v4 = *(const uint2*)(t2 + (size_t)eidx[j + 4] * 128 + lane * 8);
            uint2 v5 = *(const uint2*)(t2 + (size_t)eidx[j + 5] * 128 + lane * 8);
            uint2 v6 = *(const uint2*)(t2 + (size_t)eidx[j + 6] * 128 + lane * 8);
            uint2 v7 = *(const uint2*)(t2 + (size_t)eidx[j + 7] * 128 + lane * 8);
            acc8(a0, v0); acc8(a1, v1); acc8(a2, v2); acc8(a3, v3);
            acc8(a0, v4); acc8(a1, v5); acc8(a2, v6); acc8(a3, v7);
        }
        for (; j + 3 < end; j += 4) {
            uint2 v0 = *(const uint2*)(t2 + (size_t)eidx[j] * 128 + lane * 8);
            uint2 v1 = *(const uint2*)(t2 + (size_t)eidx[j + 1] * 128 + lane * 8);
            uint2 v2 = *(const uint2*)(t2 + (size_t)eidx[j + 2] * 128 + lane * 8);
            uint2 v3 = *(const uint2*)(t2 + (size_t)eidx[j + 3] * 128 + lane * 8);
            acc8(a0, v0); acc8(a1, v1); acc8(a2, v2); acc8(a3, v3);
        }
        for (; j < end; ++j) {
            uint2 v0 = *(const uint2*)(t2 + (size_t)eidx[j] * 128 + lane * 8);
            acc8(a0, v0);
        }
        float d = dinv[node];
        short8 rv = *(const short8*)(r2 + (size_t)node * 128 + lane * 8);
        float4 ba = ld4(b2 + lane * 8), bb = ld4(b2 + lane * 8 + 4);
        float bc[8] = {ba.x, ba.y, ba.z, ba.w, bb.x, bb.y, bb.z, bb.w};
        short8 o;
        #pragma unroll
        for (int i = 0; i < 8; ++i)
            o[i] = f2bf(fmaxf(((a0[i] + a1[i]) + (a2[i] + a3[i])) * d + bf2f((ushort_t)rv[i]) + bc[i], 0.0f));
        *(short8*)(As + nl * KP + lane * 8) = o;
    }
    __syncthreads();
    const int w = tid >> 6, lane64 = tid & 63;
    const int ln = lane64 & 15, quad = lane64 >> 4;
    short8 a[4];
    #pragma unroll
    for (int s = 0; s < 4; ++s)
        a[s] = *(const short8*)(As + ln * KP + s * 32 + quad * 8);
    floatx4 acc = {};
    const ushort_t* bp = B3t + (size_t)(w * 16 + ln) * 128 + quad * 8;
    #pragma unroll
    for (int s = 0; s < 4; ++s) {
        short8 b = *(const short8*)(bp + s * 32);
        acc = __builtin_amdgcn_mfma_f32_16x16x32_bf16(a[s], b, acc, 0, 0, 0);
    }
    const int r0 = nb + quad * 4;
    const int ncol = w * 16 + ln;
    #pragma unroll
    for (int g = 0; g < 4; ++g) {
        int rr = r0 + g;
        float v = acc[g];
        if (ncol < 32) tml[(size_t)rr * 32 + ncol] = f2bf(v);
        else rml[(size_t)rr * 32 + (ncol - 32)] = v;
    }
}

// ---------------- gather 3 (8 lanes/node, 32 nodes/block, 8-deep unroll) ----------------
__global__ __launch_bounds__(256) void gather3_kernel(
    const ushort_t* __restrict__ tml, const float* __restrict__ rml,
    const int* __restrict__ row_beg, const int* __restrict__ row_end,
    const ushort_t* __restrict__ eidx, const float* __restrict__ dinv,
    const float* __restrict__ bmu, const float* __restrict__ bls,
    float* __restrict__ out) {
    const int lane = threadIdx.x & 7;          // 8 lanes/node, 4 bf16 each
    const int nl = threadIdx.x >> 3;
    const int n = blockIdx.x * 32 + nl;
    if (n >= N_NODES) return;
    const int beg = row_beg[n], end = row_end[n];
    float a0[4] = {}, a1[4] = {}, a2[4] = {}, a3[4] = {};
    int j = beg;
    for (; j + 7 < end; j += 8) {
        short4v v0 = *(const short4v*)(tml + (size_t)eidx[j] * 32 + lane * 4);
        short4v v1 = *(const short4v*)(tml + (size_t)eidx[j + 1] * 32 + lane * 4);
        short4v v2 = *(const short4v*)(tml + (size_t)eidx[j + 2] * 32 + lane * 4);
        short4v v3 = *(const short4v*)(tml + (size_t)eidx[j + 3] * 32 + lane * 4);
        short4v v4 = *(const short4v*)(tml + (size_t)eidx[j + 4] * 32 + lane * 4);
        short4v v5 = *(const short4v*)(tml + (size_t)eidx[j + 5] * 32 + lane * 4);
        short4v v6 = *(const short4v*)(tml + (size_t)eidx[j + 6] * 32 + lane * 4);
        short4v v7 = *(const short4v*)(tml + (size_t)eidx[j + 7] * 32 + lane * 4);
        #pragma unroll
        for (int i = 0; i < 4; ++i) {
            a0[i] += bf2f((ushort_t)v0[i]); a1[i] += bf2f((ushort_t)v1[i]);
            a2[i] += bf2f((ushort_t)v2[i]); a3[i] += bf2f((ushort_t)v3[i]);
            a0[i] += bf2f((ushort_t)v4[i]); a1[i] += bf2f((ushort_t)v5[i]);
            a2[i] += bf2f((ushort_t)v6[i]); a3[i] += bf2f((ushort_t)v7[i]);
        }
    }
    for (; j + 3 < end; j += 4) {
        short4v v0 = *(const short4v*)(tml + (size_t)eidx[j] * 32 + lane * 4);
        short4v v1 = *(const short4v*)(tml + (size_t)eidx[j + 1] * 32 + lane * 4);
        short4v v2 = *(const short4v*)(tml + (size_t)eidx[j + 2] * 32 + lane * 4);
        short4v v3 = *(const short4v*)(tml + (size_t)eidx[j + 3] * 32 + lane * 4);
        #pragma unroll
        for (int i = 0; i < 4; ++i) {
            a0[i] += bf2f((ushort_t)v0[i]); a1[i] += bf2f((ushort_t)v1[i]);
            a2[i] += bf2f((ushort_t)v2[i]); a3[i] += bf2f((ushort_t)v3[i]);
        }
    }
    for (; j < end; ++j) {
        short4v v0 = *(const short4v*)(tml + (size_t)eidx[j] * 32 + lane * 4);
        #pragma unroll
        for (int i = 0; i < 4; ++i) a0[i] += bf2f((ushort_t)v0[i]);
    }
    float d = dinv[n];
    const float* bias = (lane < 4) ? (bmu + lane * 4) : (bls + (lane - 4) * 4);
    float4 ra = ld4(rml + (size_t)n * 32 + lane * 4);
    float4 ba = ld4(bias);
    float rr[4] = {ra.x, ra.y, ra.z, ra.w};
    float bc[4] = {ba.x, ba.y, ba.z, ba.w};
    float res[4];
    #pragma unroll
    for (int i = 0; i < 4; ++i) res[i] = ((a0[i] + a1[i]) + (a2[i] + a3[i])) * d + rr[i] + bc[i];
    float* base = (lane < 4) ? (out + (size_t)n * 16 + lane * 4)
                             : (out + 800000u + (size_t)n * 16 + (lane - 4) * 4);
    *(float4*)(base) = make_float4(res[0], res[1], res[2], res[3]);
}

extern "C" void kernel_launch(void* const* d_in, const int* in_sizes, int n_in,
                              void* d_out, int out_size, void* d_ws, size_t ws_size,
                              hipStream_t stream) {
    const float* x       = (const float*)d_in[0];
    const float* W1_rel  = (const float*)d_in[1];
    const float* b1      = (const float*)d_in[2];
    const float* W1_root = (const float*)d_in[3];
    const float* W2_rel  = (const float*)d_in[4];
    const float* b2      = (const float*)d_in[5];
    const float* W2_root = (const float*)d_in[6];
    const float* Wmu_rel = (const float*)d_in[7];
    const float* bmu     = (const float*)d_in[8];
    const float* Wmu_root= (const float*)d_in[9];
    const float* Wls_rel = (const float*)d_in[10];
    const float* bls     = (const float*)d_in[11];
    const float* Wls_root= (const float*)d_in[12];
    const int*   ei      = (const int*)d_in[13];
    const int* src = ei;
    const int* dst = ei + N_EDGES;

    // ---- workspace layout ----
    int*      bcursor = (int*)d_ws;                      //       256
    int*      row_beg = bcursor + 256;                   //    50,048
    int*      row_end = row_beg + 50048;                 //    50,048
    unsigned* pairbuf = (unsigned*)(row_end + 50048);    // 1,003,520
    ushort_t* eidx    = (ushort_t*)(pairbuf + 1003520);  // 1,003,520 ush
    float*    dinv    = (float*)(eidx + 1003520);        //    50,000
    ushort_t* xb   = (ushort_t*)(dinv + 50000);          //  3,200,000 ush [N,64] bf16
    uchar_t*  xq   = (uchar_t*)(xb + 3200000);           //  3,200,000 B   [N,64] fp8
    uchar_t*  t2   = xq + 3200000;                       //  6,400,000 B   [N,128] fp8
    ushort_t* r2   = (ushort_t*)(t2 + 6400000);          //  6,400,000 ush [N,128] bf16
    ushort_t* tml  = r2 + 6400000;                       //  1,600,000 ush [N,32]  bf16
    ushort_t* B1t  = tml + 1600000;                      //     32,768
    ushort_t* B2t  = B1t + 32768;                        //     65,536
    ushort_t* B3t  = B2t + 65536;                        //      8,192
    float* rml     = (float*)(B3t + 8192);               //  1,600,000 f32 [N,32]
    float* out     = (float*)d_out;

    // ---- merged prep + partition (bcursor relative, zeroed) ----
    hipMemsetAsync(bcursor, 0, 256 * sizeof(int), stream);
    prep_part_kernel<<<PREPBLK + PBLK, 256, 0, stream>>>(
        x, W1_rel, W1_root, W2_rel, W2_root, Wmu_rel, Wls_rel, Wmu_root, Wls_root,
        src, dst, xb, xq, B1t, B2t, B3t, bcursor, pairbuf);
    fill_bucket_kernel<<<NBUCK, 1024, 0, stream>>>(pairbuf, bcursor, row_beg, row_end, dinv, eidx);

    // ---- fused layer1 gather + gemm1 + gemm2 ----
    g1gemm12<<<782, 256, 0, stream>>>(xb, xq, row_beg, row_end, eidx, dinv,
                                      B1t, b1, B2t, t2, r2);

    // ---- layer 2 gather + fused layer-3 transform ----
    g2g3_kernel<<<3125, 256, 0, stream>>>(t2, r2, row_beg, row_end, eidx, dinv, b2, B3t, tml, rml);

    // ---- mu / logstd final aggregation ----
    gather3_kernel<<<1563, 256, 0, stream>>>(tml, rml, row_beg, row_end, eidx, dinv, bmu, bls, out);
}

// Round 9
// 194.629 us; speedup vs baseline: 1.0257x; 1.0257x over previous
//
#include <hip/hip_runtime.h>
#include <hip/hip_fp8.h>

#define N_NODES 50000
#define N_EDGES 800000
#define NBUCK 196       // ceil(50000/256) buckets of 256 nodes
#define PBLK 391        // ceil(800000/2048) partition blocks
#define CAP 5120        // bucket window capacity

typedef unsigned short ushort_t;
typedef unsigned char uchar_t;
typedef short short8 __attribute__((ext_vector_type(8)));
typedef short short4v __attribute__((ext_vector_type(4)));
typedef float floatx4 __attribute__((ext_vector_type(4)));
typedef float floatx2 __attribute__((ext_vector_type(2)));

__device__ __forceinline__ float bf2f(ushort_t u) {
    unsigned v = ((unsigned)u) << 16;
    return __builtin_bit_cast(float, v);
}
__device__ __forceinline__ ushort_t f2bf(float f) {
    unsigned u = __builtin_bit_cast(unsigned, f);
    unsigned r = (u + 0x7FFFu + ((u >> 16) & 1u)) >> 16;  // RNE
    return (ushort_t)r;
}
// HW OCP fp8 converts (gfx950)
__device__ __forceinline__ uchar_t f2fp8(float f) {
    return (uchar_t)(__builtin_amdgcn_cvt_pk_fp8_f32(f, f, 0, false) & 0xFF);
}
__device__ __forceinline__ float4 ld4(const float* p) { return *(const float4*)p; }

// LDS-only barrier: waits lgkm (ds ops) but leaves global prefetch loads (vmcnt) in flight.
// __syncthreads() would drain vmcnt(0) and defeat the B-strip register prefetch.
__device__ __forceinline__ void lite_barrier() {
    asm volatile("s_waitcnt lgkmcnt(0)" ::: "memory");
    __builtin_amdgcn_s_barrier();
}

__device__ __forceinline__ void acc16(float* a, uint4 v) {
    unsigned ws[4] = {v.x, v.y, v.z, v.w};
    #pragma unroll
    for (int wi = 0; wi < 4; ++wi) {
        floatx2 lo = __builtin_amdgcn_cvt_pk_f32_fp8(ws[wi], false);
        floatx2 hi = __builtin_amdgcn_cvt_pk_f32_fp8(ws[wi], true);
        a[wi * 4 + 0] += lo.x; a[wi * 4 + 1] += lo.y;
        a[wi * 4 + 2] += hi.x; a[wi * 4 + 3] += hi.y;
    }
}
__device__ __forceinline__ void acc8(float* a, uint2 v) {
    floatx2 p0 = __builtin_amdgcn_cvt_pk_f32_fp8(v.x, false);
    floatx2 p1 = __builtin_amdgcn_cvt_pk_f32_fp8(v.x, true);
    floatx2 p2 = __builtin_amdgcn_cvt_pk_f32_fp8(v.y, false);
    floatx2 p3 = __builtin_amdgcn_cvt_pk_f32_fp8(v.y, true);
    a[0] += p0.x; a[1] += p0.y; a[2] += p1.x; a[3] += p1.y;
    a[4] += p2.x; a[5] += p2.y; a[6] += p3.x; a[7] += p3.y;
}

// ---------------- prep: cvt_x (bf16 + fp8) + cvt_w + bucket cursor init ----------------
__global__ __launch_bounds__(256) void prep_kernel(
    const float* __restrict__ x,
    const float* __restrict__ W1_rel, const float* __restrict__ W1_root,
    const float* __restrict__ W2_rel, const float* __restrict__ W2_root,
    const float* __restrict__ Wmu_rel, const float* __restrict__ Wls_rel,
    const float* __restrict__ Wmu_root, const float* __restrict__ Wls_root,
    ushort_t* __restrict__ xb, uchar_t* __restrict__ xq,
    ushort_t* __restrict__ B1t, ushort_t* __restrict__ B2t, ushort_t* __restrict__ B3t,
    int* __restrict__ bcursor) {
    int idx = blockIdx.x * blockDim.x + threadIdx.x;
    if (idx < 400000) {                       // xb[n,:] = bf16(x); xq[n,:] = fp8(x)
        int n = idx >> 3, c = (idx & 7) * 8;
        float4 v0 = ld4(x + (size_t)n * 64 + c);
        float4 v1 = ld4(x + (size_t)n * 64 + c + 4);
        float vv[8] = {v0.x, v0.y, v0.z, v0.w, v1.x, v1.y, v1.z, v1.w};
        short8 o;
        #pragma unroll
        for (int i = 0; i < 8; ++i) o[i] = f2bf(vv[i]);
        int q0 = __builtin_amdgcn_cvt_pk_fp8_f32(vv[0], vv[1], 0, false);
        q0 = __builtin_amdgcn_cvt_pk_fp8_f32(vv[2], vv[3], q0, true);
        int q1 = __builtin_amdgcn_cvt_pk_fp8_f32(vv[4], vv[5], 0, false);
        q1 = __builtin_amdgcn_cvt_pk_fp8_f32(vv[6], vv[7], q1, true);
        *(short8*)(xb + (size_t)n * 64 + c) = o;
        uint2 q = {(unsigned)q0, (unsigned)q1};
        *(uint2*)(xq + (size_t)n * 64 + c) = q;
    } else if (idx < 506496) {                // transposed bf16 weights
        int j = idx - 400000;
        if (j < 32768) {
            int n = j >> 7, k = j & 127;
            float v = (k < 64) ? W1_rel[k * 256 + n] : W1_root[(k - 64) * 256 + n];
            B1t[j] = f2bf(v);
        } else if (j < 98304) {
            int jj = j - 32768;
            int n = jj >> 8, k = jj & 255;
            float v = (n < 128) ? W2_rel[k * 128 + n] : W2_root[k * 128 + (n - 128)];
            B2t[jj] = f2bf(v);
        } else {
            int jj = j - 98304;
            int n = jj >> 7, k = jj & 127;
            const float* W = (n < 16) ? Wmu_rel : (n < 32) ? Wls_rel : (n < 48) ? Wmu_root : Wls_root;
            B3t[jj] = f2bf(W[k * 16 + (n & 15)]);
        }
    } else if (idx < 506496 + NBUCK) {
        int b = idx - 506496;
        bcursor[b] = b * CAP;
    }
}

// ---------------- single-pass partition into fixed bucket windows (512 thr) ----------------
__global__ __launch_bounds__(512) void partition_kernel(
    const int* __restrict__ src, const int* __restrict__ dst,
    int* __restrict__ bcursor, unsigned* __restrict__ pairbuf) {
    __shared__ int h[NBUCK];
    __shared__ int cur[NBUCK];
    const int tid = threadIdx.x;
    for (int i = tid; i < NBUCK; i += 512) h[i] = 0;
    __syncthreads();
    const int base = blockIdx.x * 2048;
    int d[4];
    #pragma unroll
    for (int j = 0; j < 4; ++j) {
        int e = base + j * 512 + tid;
        if (e < N_EDGES) { d[j] = dst[e]; atomicAdd(&h[d[j] >> 8], 1); }
        else d[j] = -1;
    }
    __syncthreads();
    for (int i = tid; i < NBUCK; i += 512) {
        int c = h[i];
        cur[i] = c ? atomicAdd(&bcursor[i], c) : 0;
    }
    __syncthreads();
    #pragma unroll
    for (int j = 0; j < 4; ++j) {
        int e = base + j * 512 + tid;
        if (e < N_EDGES) {
            int dd = d[j];
            int slot = atomicAdd(&cur[dd >> 8], 1);
            pairbuf[slot] = (unsigned)src[e] | ((unsigned)(dd & 255) << 16);
        }
    }
}

// per-bucket (1024 thr): node histogram + scan -> row_beg/row_end/dinv; LDS-cursor eidx fill
__global__ __launch_bounds__(1024) void fill_bucket_kernel(
    const unsigned* __restrict__ pairbuf, const int* __restrict__ bcursor,
    int* __restrict__ row_beg, int* __restrict__ row_end,
    float* __restrict__ dinv, ushort_t* __restrict__ eidx) {
    __shared__ int h[256];
    __shared__ int sm[256];
    __shared__ int cur[256];
    const int b = blockIdx.x, tid = threadIdx.x;
    const int beg = b * CAP, end = bcursor[b];
    if (tid < 256) h[tid] = 0;
    __syncthreads();
    for (int i = beg + tid; i < end; i += 1024)
        atomicAdd(&h[pairbuf[i] >> 16], 1);
    __syncthreads();
    if (tid < 256) sm[tid] = h[tid];
    __syncthreads();
    #pragma unroll
    for (int off = 1; off < 256; off <<= 1) {
        int t = 0;
        if (tid < 256 && tid >= off) t = sm[tid - off];
        __syncthreads();
        if (tid < 256) sm[tid] += t;
        __syncthreads();
    }
    if (tid < 256) {
        int c = h[tid];
        int exc = beg + sm[tid] - c;
        int node = b * 256 + tid;
        if (node < N_NODES) {
            row_beg[node] = exc;
            row_end[node] = exc + c;
            dinv[node] = c > 0 ? 1.0f / (float)c : 0.0f;
        }
        cur[tid] = exc;
    }
    __syncthreads();
    for (int i = beg + tid; i < end; i += 1024) {
        unsigned v = pairbuf[i];
        int slot = atomicAdd(&cur[v >> 16], 1);
        eidx[slot] = (ushort_t)(v & 0xFFFFu);
    }
}

// ---------------- fused gather1 + gemm1 + gemm2 (50 KB LDS -> 3 blocks/CU) ----------------
__global__ __launch_bounds__(256, 3) void g1gemm12(
    const ushort_t* __restrict__ xb, const uchar_t* __restrict__ xq,
    const int* __restrict__ row_beg, const int* __restrict__ row_end,
    const ushort_t* __restrict__ eidx, const float* __restrict__ dinv,
    const ushort_t* __restrict__ B1t, const float* __restrict__ b1,
    const ushort_t* __restrict__ B2t,
    uchar_t* __restrict__ t2, ushort_t* __restrict__ r2) {
    constexpr int K1 = 128, K2 = 256;
    constexpr int AKP = 72;    // agg tile pitch (64+8)
    constexpr int HKP = 264;   // h1 tile pitch (256+8)
    constexpr int BKP = 136;   // B strip pitch (128+8)
    __shared__ ushort_t Bs[64 * BKP];   // 17.4 KB (As aliased during phase 0)
    __shared__ ushort_t Hs[64 * HKP];   // 33.8 KB (out-tiles aliased after a2 consumed)
    ushort_t* As = Bs;
    const int tid = threadIdx.x;
    const int rowbase = blockIdx.x * 64;

    // ---- phase 0: gather mean of fp8 neighbor rows ----
    {
        const int nl = tid >> 2, lane = tid & 3;   // 4 lanes/node, 16 fp8 each
        const int node = rowbase + nl;
        int beg = 0, end = 0;
        float d = 0.0f;
        if (node < N_NODES) { beg = row_beg[node]; end = row_end[node]; d = dinv[node]; }
        float a0[16] = {}, a1[16] = {};
        int j = beg;
        for (; j + 3 < end; j += 4) {
            uint4 v0 = *(const uint4*)(xq + (size_t)eidx[j] * 64 + lane * 16);
            uint4 v1 = *(const uint4*)(xq + (size_t)eidx[j + 1] * 64 + lane * 16);
            uint4 v2 = *(const uint4*)(xq + (size_t)eidx[j + 2] * 64 + lane * 16);
            uint4 v3 = *(const uint4*)(xq + (size_t)eidx[j + 3] * 64 + lane * 16);
            acc16(a0, v0); acc16(a1, v1); acc16(a0, v2); acc16(a1, v3);
        }
        for (; j < end; ++j) {
            uint4 v0 = *(const uint4*)(xq + (size_t)eidx[j] * 64 + lane * 16);
            acc16(a0, v0);
        }
        short8 o0, o1;
        #pragma unroll
        for (int i = 0; i < 8; ++i) {
            o0[i] = f2bf((a0[i] + a1[i]) * d);
            o1[i] = f2bf((a0[8 + i] + a1[8 + i]) * d);
        }
        *(short8*)(As + nl * AKP + lane * 16) = o0;
        *(short8*)(As + nl * AKP + lane * 16 + 8) = o1;
    }
    __syncthreads();

    const int w = tid >> 6, lane64 = tid & 63;
    const int ln = lane64 & 15, quad = lane64 >> 4;
    const int rwl = w * 16 + ln;
    int r = rowbase + rwl;
    if (r > N_NODES - 1) r = N_NODES - 1;

    float bias[4][4];
    #pragma unroll
    for (int ny = 0; ny < 4; ++ny)
        #pragma unroll
        for (int f = 0; f < 4; ++f)
            bias[ny][f] = b1[ny * 64 + f * 16 + ln];

    // ---- phase 1: gemm1, A = [As | xb], B staged with reg-prefetch + light barriers ----
    short8 a[4];
    a[0] = *(const short8*)(As + rwl * AKP + quad * 8);
    a[1] = *(const short8*)(As + rwl * AKP + 32 + quad * 8);
    a[2] = *(const short8*)(xb + (size_t)r * 64 + quad * 8);
    a[3] = *(const short8*)(xb + (size_t)r * 64 + 32 + quad * 8);
    {
        short8 pb[4];
        #pragma unroll
        for (int i = 0; i < 4; ++i) {
            int idx = tid + i * 256, row = idx >> 4, off = (idx & 15) * 8;
            pb[i] = *(const short8*)(B1t + (size_t)row * K1 + off);
        }
        for (int ny = 0; ny < 4; ++ny) {
            lite_barrier();                    // Bs free (prev reads drained; As reads drained)
            #pragma unroll
            for (int i = 0; i < 4; ++i) {
                int idx = tid + i * 256, row = idx >> 4, off = (idx & 15) * 8;
                *(short8*)(Bs + row * BKP + off) = pb[i];
            }
            if (ny < 3) {
                #pragma unroll
                for (int i = 0; i < 4; ++i) {
                    int idx = tid + i * 256, row = idx >> 4, off = (idx & 15) * 8;
                    pb[i] = *(const short8*)(B1t + (size_t)((ny + 1) * 64 + row) * K1 + off);
                }
            }
            lite_barrier();                    // Bs ready; prefetch stays in flight (no vmcnt drain)
            floatx4 acc[4] = {};
            #pragma unroll
            for (int f = 0; f < 4; ++f) {
                const ushort_t* bp = Bs + (f * 16 + ln) * BKP + quad * 8;
                #pragma unroll
                for (int s = 0; s < 4; ++s) {
                    short8 b = *(const short8*)(bp + s * 32);
                    acc[f] = __builtin_amdgcn_mfma_f32_16x16x32_bf16(a[s], b, acc[f], 0, 0, 0);
                }
            }
            #pragma unroll
            for (int f = 0; f < 4; ++f) {
                int n = ny * 64 + f * 16 + ln;
                #pragma unroll
                for (int g = 0; g < 4; ++g) {
                    int rr = w * 16 + quad * 4 + g;
                    Hs[rr * HKP + n] = f2bf(fmaxf(acc[f][g] + bias[ny][f], 0.0f));
                }
            }
        }
    }
    __syncthreads();

    // ---- phase 2: gemm2, A = Hs (to regs; Hs region becomes output tiles) ----
    short8 a2[8];
    #pragma unroll
    for (int s = 0; s < 8; ++s)
        a2[s] = *(const short8*)(Hs + rwl * HKP + s * 32 + quad * 8);
    ushort_t* Or16 = Hs;                          // pitch 136 ush (bf16 tile)
    uchar_t*  Ot8  = (uchar_t*)(Hs + 8704);       // pitch 144 B (fp8 tile)
    {
        short8 pb[4];
        #pragma unroll
        for (int i = 0; i < 4; ++i) {
            int idx = tid + i * 256, row = idx >> 4, off = (idx & 15) * 8;
            pb[i] = *(const short8*)(B2t + (size_t)row * K2 + off);
        }
        for (int ny = 0; ny < 4; ++ny) {
            floatx4 acc[4] = {};
            #pragma unroll
            for (int kh = 0; kh < 2; ++kh) {
                lite_barrier();                // Bs free; a2/prev reads drained
                #pragma unroll
                for (int i = 0; i < 4; ++i) {
                    int idx = tid + i * 256, row = idx >> 4, off = (idx & 15) * 8;
                    *(short8*)(Bs + row * BKP + off) = pb[i];
                }
                int st = ny * 2 + kh;
                if (st < 7) {
                    int nyn = (st + 1) >> 1, khn = (st + 1) & 1;
                    #pragma unroll
                    for (int i = 0; i < 4; ++i) {
                        int idx = tid + i * 256, row = idx >> 4, off = (idx & 15) * 8;
                        pb[i] = *(const short8*)(B2t + (size_t)(nyn * 64 + row) * K2 + khn * 128 + off);
                    }
                }
                lite_barrier();                // Bs ready; prefetch stays in flight
                #pragma unroll
                for (int f = 0; f < 4; ++f) {
                    const ushort_t* bp = Bs + (f * 16 + ln) * BKP + quad * 8;
                    #pragma unroll
                    for (int s = 0; s < 4; ++s) {
                        short8 b = *(const short8*)(bp + s * 32);
                        acc[f] = __builtin_amdgcn_mfma_f32_16x16x32_bf16(a2[kh * 4 + s], b, acc[f], 0, 0, 0);
                    }
                }
            }
            #pragma unroll
            for (int f = 0; f < 4; ++f) {
                int n = ny * 64 + f * 16 + ln;
                #pragma unroll
                for (int g = 0; g < 4; ++g) {
                    int rr = w * 16 + quad * 4 + g;
                    float v = acc[f][g];
                    if (n < 128) Ot8[rr * 144 + n] = f2fp8(v);
                    else Or16[rr * 136 + (n - 128)] = f2bf(v);
                }
            }
        }
    }
    __syncthreads();

    // ---- coalesced store-out of both tiles ----
    {
        const int row = tid >> 2, seg = tid & 3;
        const int gr = rowbase + row;
        if (gr < N_NODES) {
            const uint4* ps = (const uint4*)(Ot8 + row * 144 + seg * 32);
            uint4* pd = (uint4*)(t2 + (size_t)gr * 128 + seg * 32);
            pd[0] = ps[0]; pd[1] = ps[1];
            const uint4* qs = (const uint4*)(Or16 + row * 136 + seg * 32);
            uint4* qd = (uint4*)(r2 + (size_t)gr * 128 + seg * 32);
            qd[0] = qs[0]; qd[1] = qs[1]; qd[2] = qs[2]; qd[3] = qs[3];
        }
    }
}

// ---------------- fused gather2 + combine + gemm3 (16 nodes/block, 16 threads/node) ----------------
__global__ __launch_bounds__(256) void g2g3_kernel(
    const uchar_t* __restrict__ t2, const ushort_t* __restrict__ r2,
    const int* __restrict__ row_beg, const int* __restrict__ row_end,
    const ushort_t* __restrict__ eidx, const float* __restrict__ dinv,
    const float* __restrict__ b2, const ushort_t* __restrict__ B3t,
    ushort_t* __restrict__ tml, float* __restrict__ rml) {
    constexpr int KP = 136;
    __shared__ ushort_t As[16 * KP];
    const int tid = threadIdx.x;
    const int nb = blockIdx.x * 16;   // 3125*16 = 50000 exact
    {
        const int nl = tid >> 4, lane = tid & 15;
        const int node = nb + nl;
        const int beg = row_beg[node], end = row_end[node];
        float a0[8] = {}, a1[8] = {}, a2[8] = {}, a3[8] = {};
        int j = beg;
        for (; j + 3 < end; j += 4) {
            uint2 v0 = *(const uint2*)(t2 + (size_t)eidx[j] * 128 + lane * 8);
            uint2 v1 = *(const uint2*)(t2 + (size_t)eidx[j + 1] * 128 + lane * 8);
            uint2 v2 = *(const uint2*)(t2 + (size_t)eidx[j + 2] * 128 + lane * 8);
            uint2 v3 = *(const uint2*)(t2 + (size_t)eidx[j + 3] * 128 + lane * 8);
            acc8(a0, v0); acc8(a1, v1); acc8(a2, v2); acc8(a3, v3);
        }
        for (; j < end; ++j) {
            uint2 v0 = *(const uint2*)(t2 + (size_t)eidx[j] * 128 + lane * 8);
            acc8(a0, v0);
        }
        float d = dinv[node];
        short8 rv = *(const short8*)(r2 + (size_t)node * 128 + lane * 8);
        float4 ba = ld4(b2 + lane * 8), bb = ld4(b2 + lane * 8 + 4);
        float bc[8] = {ba.x, ba.y, ba.z, ba.w, bb.x, bb.y, bb.z, bb.w};
        short8 o;
        #pragma unroll
        for (int i = 0; i < 8; ++i)
            o[i] = f2bf(fmaxf(((a0[i] + a1[i]) + (a2[i] + a3[i])) * d + bf2f((ushort_t)rv[i]) + bc[i], 0.0f));
        *(short8*)(As + nl * KP + lane * 8) = o;
    }
    __syncthreads();
    const int w = tid >> 6, lane64 = tid & 63;
    const int ln = lane64 & 15, quad = lane64 >> 4;
    short8 a[4];
    #pragma unroll
    for (int s = 0; s < 4; ++s)
        a[s] = *(const short8*)(As + ln * KP + s * 32 + quad * 8);
    floatx4 acc = {};
    const ushort_t* bp = B3t + (size_t)(w * 16 + ln) * 128 + quad * 8;
    #pragma unroll
    for (int s = 0; s < 4; ++s) {
        short8 b = *(const short8*)(bp + s * 32);
        acc = __builtin_amdgcn_mfma_f32_16x16x32_bf16(a[s], b, acc, 0, 0, 0);
    }
    const int r0 = nb + quad * 4;
    const int ncol = w * 16 + ln;
    #pragma unroll
    for (int g = 0; g < 4; ++g) {
        int rr = r0 + g;
        float v = acc[g];
        if (ncol < 32) tml[(size_t)rr * 32 + ncol] = f2bf(v);
        else rml[(size_t)rr * 32 + (ncol - 32)] = v;
    }
}

// ---------------- gather 3 (8 lanes/node, 32 nodes/block, fused combine + split write) ----
__global__ __launch_bounds__(256) void gather3_kernel(
    const ushort_t* __restrict__ tml, const float* __restrict__ rml,
    const int* __restrict__ row_beg, const int* __restrict__ row_end,
    const ushort_t* __restrict__ eidx, const float* __restrict__ dinv,
    const float* __restrict__ bmu, const float* __restrict__ bls,
    float* __restrict__ out) {
    const int lane = threadIdx.x & 7;          // 8 lanes/node, 4 bf16 each
    const int nl = threadIdx.x >> 3;
    const int n = blockIdx.x * 32 + nl;
    if (n >= N_NODES) return;
    const int beg = row_beg[n], end = row_end[n];
    float a0[4] = {}, a1[4] = {}, a2[4] = {}, a3[4] = {};
    int j = beg;
    for (; j + 3 < end; j += 4) {
        short4v v0 = *(const short4v*)(tml + (size_t)eidx[j] * 32 + lane * 4);
        short4v v1 = *(const short4v*)(tml + (size_t)eidx[j + 1] * 32 + lane * 4);
        short4v v2 = *(const short4v*)(tml + (size_t)eidx[j + 2] * 32 + lane * 4);
        short4v v3 = *(const short4v*)(tml + (size_t)eidx[j + 3] * 32 + lane * 4);
        #pragma unroll
        for (int i = 0; i < 4; ++i) {
            a0[i] += bf2f((ushort_t)v0[i]); a1[i] += bf2f((ushort_t)v1[i]);
            a2[i] += bf2f((ushort_t)v2[i]); a3[i] += bf2f((ushort_t)v3[i]);
        }
    }
    for (; j < end; ++j) {
        short4v v0 = *(const short4v*)(tml + (size_t)eidx[j] * 32 + lane * 4);
        #pragma unroll
        for (int i = 0; i < 4; ++i) a0[i] += bf2f((ushort_t)v0[i]);
    }
    float d = dinv[n];
    const float* bias = (lane < 4) ? (bmu + lane * 4) : (bls + (lane - 4) * 4);
    float4 ra = ld4(rml + (size_t)n * 32 + lane * 4);
    float4 ba = ld4(bias);
    float rr[4] = {ra.x, ra.y, ra.z, ra.w};
    float bc[4] = {ba.x, ba.y, ba.z, ba.w};
    float res[4];
    #pragma unroll
    for (int i = 0; i < 4; ++i) res[i] = ((a0[i] + a1[i]) + (a2[i] + a3[i])) * d + rr[i] + bc[i];
    float* base = (lane < 4) ? (out + (size_t)n * 16 + lane * 4)
                             : (out + 800000u + (size_t)n * 16 + (lane - 4) * 4);
    *(float4*)(base) = make_float4(res[0], res[1], res[2], res[3]);
}

extern "C" void kernel_launch(void* const* d_in, const int* in_sizes, int n_in,
                              void* d_out, int out_size, void* d_ws, size_t ws_size,
                              hipStream_t stream) {
    const float* x       = (const float*)d_in[0];
    const float* W1_rel  = (const float*)d_in[1];
    const float* b1      = (const float*)d_in[2];
    const float* W1_root = (const float*)d_in[3];
    const float* W2_rel  = (const float*)d_in[4];
    const float* b2      = (const float*)d_in[5];
    const float* W2_root = (const float*)d_in[6];
    const float* Wmu_rel = (const float*)d_in[7];
    const float* bmu     = (const float*)d_in[8];
    const float* Wmu_root= (const float*)d_in[9];
    const float* Wls_rel = (const float*)d_in[10];
    const float* bls     = (const float*)d_in[11];
    const float* Wls_root= (const float*)d_in[12];
    const int*   ei      = (const int*)d_in[13];
    const int* src = ei;
    const int* dst = ei + N_EDGES;

    // ---- workspace layout ----
    int*      bcursor = (int*)d_ws;                      //       256
    int*      row_beg = bcursor + 256;                   //    50,048
    int*      row_end = row_beg + 50048;                 //    50,048
    unsigned* pairbuf = (unsigned*)(row_end + 50048);    // 1,003,520
    ushort_t* eidx    = (ushort_t*)(pairbuf + 1003520);  // 1,003,520 ush
    float*    dinv    = (float*)(eidx + 1003520);        //    50,000
    ushort_t* xb   = (ushort_t*)(dinv + 50000);          //  3,200,000 ush [N,64] bf16
    uchar_t*  xq   = (uchar_t*)(xb + 3200000);           //  3,200,000 B   [N,64] fp8
    uchar_t*  t2   = xq + 3200000;                       //  6,400,000 B   [N,128] fp8
    ushort_t* r2   = (ushort_t*)(t2 + 6400000);          //  6,400,000 ush [N,128] bf16
    ushort_t* tml  = r2 + 6400000;                       //  1,600,000 ush [N,32]  bf16
    ushort_t* B1t  = tml + 1600000;                      //     32,768
    ushort_t* B2t  = B1t + 32768;                        //     65,536
    ushort_t* B3t  = B2t + 65536;                        //      8,192
    float* rml     = (float*)(B3t + 8192);               //  1,600,000 f32 [N,32]
    float* out     = (float*)d_out;

    // ---- prep + CSR build ----
    prep_kernel<<<1980, 256, 0, stream>>>(x, W1_rel, W1_root, W2_rel, W2_root,
                                          Wmu_rel, Wls_rel, Wmu_root, Wls_root,
                                          xb, xq, B1t, B2t, B3t, bcursor);
    partition_kernel<<<PBLK, 512, 0, stream>>>(src, dst, bcursor, pairbuf);
    fill_bucket_kernel<<<NBUCK, 1024, 0, stream>>>(pairbuf, bcursor, row_beg, row_end, dinv, eidx);

    // ---- fused layer1 gather + gemm1 + gemm2 ----
    g1gemm12<<<782, 256, 0, stream>>>(xb, xq, row_beg, row_end, eidx, dinv,
                                      B1t, b1, B2t, t2, r2);

    // ---- layer 2 gather + fused layer-3 transform ----
    g2g3_kernel<<<3125, 256, 0, stream>>>(t2, r2, row_beg, row_end, eidx, dinv, b2, B3t, tml, rml);

    // ---- mu / logstd final aggregation ----
    gather3_kernel<<<1563, 256, 0, stream>>>(tml, rml, row_beg, row_end, eidx, dinv, bmu, bls, out);
}

// Round 10
// 192.743 us; speedup vs baseline: 1.0357x; 1.0098x over previous
//
#include <hip/hip_runtime.h>
#include <hip/hip_fp8.h>

#define N_NODES 50000
#define N_EDGES 800000
#define NBUCK 196       // ceil(50000/256) buckets of 256 nodes
#define PBLK 391        // ceil(800000/2048) partition blocks
#define CAP 5120        // bucket window capacity

typedef unsigned short ushort_t;
typedef unsigned char uchar_t;
typedef short short8 __attribute__((ext_vector_type(8)));
typedef short short4v __attribute__((ext_vector_type(4)));
typedef float floatx4 __attribute__((ext_vector_type(4)));
typedef float floatx2 __attribute__((ext_vector_type(2)));

__device__ __forceinline__ float bf2f(ushort_t u) {
    unsigned v = ((unsigned)u) << 16;
    return __builtin_bit_cast(float, v);
}
__device__ __forceinline__ ushort_t f2bf(float f) {
    unsigned u = __builtin_bit_cast(unsigned, f);
    unsigned r = (u + 0x7FFFu + ((u >> 16) & 1u)) >> 16;  // RNE
    return (ushort_t)r;
}
// HW OCP fp8 converts (gfx950)
__device__ __forceinline__ uchar_t f2fp8(float f) {
    return (uchar_t)(__builtin_amdgcn_cvt_pk_fp8_f32(f, f, 0, false) & 0xFF);
}
__device__ __forceinline__ float4 ld4(const float* p) { return *(const float4*)p; }

// LDS-only barrier: waits lgkm (ds ops) but leaves global loads/stores (vmcnt) in flight.
__device__ __forceinline__ void lite_barrier() {
    asm volatile("s_waitcnt lgkmcnt(0)" ::: "memory");
    __builtin_amdgcn_s_barrier();
}

__device__ __forceinline__ void acc16(float* a, uint4 v) {
    unsigned ws[4] = {v.x, v.y, v.z, v.w};
    #pragma unroll
    for (int wi = 0; wi < 4; ++wi) {
        floatx2 lo = __builtin_amdgcn_cvt_pk_f32_fp8(ws[wi], false);
        floatx2 hi = __builtin_amdgcn_cvt_pk_f32_fp8(ws[wi], true);
        a[wi * 4 + 0] += lo.x; a[wi * 4 + 1] += lo.y;
        a[wi * 4 + 2] += hi.x; a[wi * 4 + 3] += hi.y;
    }
}
__device__ __forceinline__ void acc8(float* a, uint2 v) {
    floatx2 p0 = __builtin_amdgcn_cvt_pk_f32_fp8(v.x, false);
    floatx2 p1 = __builtin_amdgcn_cvt_pk_f32_fp8(v.x, true);
    floatx2 p2 = __builtin_amdgcn_cvt_pk_f32_fp8(v.y, false);
    floatx2 p3 = __builtin_amdgcn_cvt_pk_f32_fp8(v.y, true);
    a[0] += p0.x; a[1] += p0.y; a[2] += p1.x; a[3] += p1.y;
    a[4] += p2.x; a[5] += p2.y; a[6] += p3.x; a[7] += p3.y;
}

// ---------------- prep: cvt_x (bf16 + fp8) + cvt_w + bucket cursor init ----------------
__global__ __launch_bounds__(256) void prep_kernel(
    const float* __restrict__ x,
    const float* __restrict__ W1_rel, const float* __restrict__ W1_root,
    const float* __restrict__ W2_rel, const float* __restrict__ W2_root,
    const float* __restrict__ Wmu_rel, const float* __restrict__ Wls_rel,
    const float* __restrict__ Wmu_root, const float* __restrict__ Wls_root,
    ushort_t* __restrict__ xb, uchar_t* __restrict__ xq,
    ushort_t* __restrict__ B1t, ushort_t* __restrict__ B2t, ushort_t* __restrict__ B3t,
    int* __restrict__ bcursor) {
    int idx = blockIdx.x * blockDim.x + threadIdx.x;
    if (idx < 400000) {                       // xb[n,:] = bf16(x); xq[n,:] = fp8(x)
        int n = idx >> 3, c = (idx & 7) * 8;
        float4 v0 = ld4(x + (size_t)n * 64 + c);
        float4 v1 = ld4(x + (size_t)n * 64 + c + 4);
        float vv[8] = {v0.x, v0.y, v0.z, v0.w, v1.x, v1.y, v1.z, v1.w};
        short8 o;
        #pragma unroll
        for (int i = 0; i < 8; ++i) o[i] = f2bf(vv[i]);
        int q0 = __builtin_amdgcn_cvt_pk_fp8_f32(vv[0], vv[1], 0, false);
        q0 = __builtin_amdgcn_cvt_pk_fp8_f32(vv[2], vv[3], q0, true);
        int q1 = __builtin_amdgcn_cvt_pk_fp8_f32(vv[4], vv[5], 0, false);
        q1 = __builtin_amdgcn_cvt_pk_fp8_f32(vv[6], vv[7], q1, true);
        *(short8*)(xb + (size_t)n * 64 + c) = o;
        uint2 q = {(unsigned)q0, (unsigned)q1};
        *(uint2*)(xq + (size_t)n * 64 + c) = q;
    } else if (idx < 506496) {                // transposed bf16 weights
        int j = idx - 400000;
        if (j < 32768) {
            int n = j >> 7, k = j & 127;
            float v = (k < 64) ? W1_rel[k * 256 + n] : W1_root[(k - 64) * 256 + n];
            B1t[j] = f2bf(v);
        } else if (j < 98304) {
            int jj = j - 32768;
            int n = jj >> 8, k = jj & 255;
            float v = (n < 128) ? W2_rel[k * 128 + n] : W2_root[k * 128 + (n - 128)];
            B2t[jj] = f2bf(v);
        } else {
            int jj = j - 98304;
            int n = jj >> 7, k = jj & 127;
            const float* W = (n < 16) ? Wmu_rel : (n < 32) ? Wls_rel : (n < 48) ? Wmu_root : Wls_root;
            B3t[jj] = f2bf(W[k * 16 + (n & 15)]);
        }
    } else if (idx < 506496 + NBUCK) {
        int b = idx - 506496;
        bcursor[b] = b * CAP;
    }
}

// ---------------- single-pass partition into fixed bucket windows (512 thr) ----------------
__global__ __launch_bounds__(512) void partition_kernel(
    const int* __restrict__ src, const int* __restrict__ dst,
    int* __restrict__ bcursor, unsigned* __restrict__ pairbuf) {
    __shared__ int h[NBUCK];
    __shared__ int cur[NBUCK];
    const int tid = threadIdx.x;
    for (int i = tid; i < NBUCK; i += 512) h[i] = 0;
    __syncthreads();
    const int base = blockIdx.x * 2048;
    int d[4];
    #pragma unroll
    for (int j = 0; j < 4; ++j) {
        int e = base + j * 512 + tid;
        if (e < N_EDGES) { d[j] = dst[e]; atomicAdd(&h[d[j] >> 8], 1); }
        else d[j] = -1;
    }
    __syncthreads();
    for (int i = tid; i < NBUCK; i += 512) {
        int c = h[i];
        cur[i] = c ? atomicAdd(&bcursor[i], c) : 0;
    }
    __syncthreads();
    #pragma unroll
    for (int j = 0; j < 4; ++j) {
        int e = base + j * 512 + tid;
        if (e < N_EDGES) {
            int dd = d[j];
            int slot = atomicAdd(&cur[dd >> 8], 1);
            pairbuf[slot] = (unsigned)src[e] | ((unsigned)(dd & 255) << 16);
        }
    }
}

// per-bucket (1024 thr): node histogram + scan -> row_beg/row_end/dinv; LDS-cursor eidx fill
__global__ __launch_bounds__(1024) void fill_bucket_kernel(
    const unsigned* __restrict__ pairbuf, const int* __restrict__ bcursor,
    int* __restrict__ row_beg, int* __restrict__ row_end,
    float* __restrict__ dinv, ushort_t* __restrict__ eidx) {
    __shared__ int h[256];
    __shared__ int sm[256];
    __shared__ int cur[256];
    const int b = blockIdx.x, tid = threadIdx.x;
    const int beg = b * CAP, end = bcursor[b];
    if (tid < 256) h[tid] = 0;
    __syncthreads();
    for (int i = beg + tid; i < end; i += 1024)
        atomicAdd(&h[pairbuf[i] >> 16], 1);
    __syncthreads();
    if (tid < 256) sm[tid] = h[tid];
    __syncthreads();
    #pragma unroll
    for (int off = 1; off < 256; off <<= 1) {
        int t = 0;
        if (tid < 256 && tid >= off) t = sm[tid - off];
        __syncthreads();
        if (tid < 256) sm[tid] += t;
        __syncthreads();
    }
    if (tid < 256) {
        int c = h[tid];
        int exc = beg + sm[tid] - c;
        int node = b * 256 + tid;
        if (node < N_NODES) {
            row_beg[node] = exc;
            row_end[node] = exc + c;
            dinv[node] = c > 0 ? 1.0f / (float)c : 0.0f;
        }
        cur[tid] = exc;
    }
    __syncthreads();
    for (int i = beg + tid; i < end; i += 1024) {
        unsigned v = pairbuf[i];
        int slot = atomicAdd(&cur[v >> 16], 1);
        eidx[slot] = (ushort_t)(v & 0xFFFFu);
    }
}

// ---------------- fused gather1 + gemm1 + gemm2 (17.4 KB LDS -> ALL 782 blocks resident) ----
// h1 tile routed through global scratch h1g (L2-local); B strips + h1/out strips all staged
// through the single Bs buffer. One dispatch round: every block starts at t=0.
__global__ __launch_bounds__(256) void g1gemm12(
    const ushort_t* __restrict__ xb, const uchar_t* __restrict__ xq,
    const int* __restrict__ row_beg, const int* __restrict__ row_end,
    const ushort_t* __restrict__ eidx, const float* __restrict__ dinv,
    const ushort_t* __restrict__ B1t, const float* __restrict__ b1,
    const ushort_t* __restrict__ B2t, ushort_t* __restrict__ h1g,
    uchar_t* __restrict__ t2, ushort_t* __restrict__ r2) {
    constexpr int K1 = 128, K2 = 256;
    constexpr int AKP = 72;    // agg/h1-strip/r2-strip pitch (64+8 ushorts, 144 B, 16B-aligned)
    constexpr int BKP = 136;   // B strip pitch (128+8)
    __shared__ ushort_t Bs[64 * BKP];   // 17.4 KB — the only LDS
    ushort_t* As = Bs;
    const int tid = threadIdx.x;
    const int rowbase = blockIdx.x * 64;

    // ---- phase 0: gather mean of fp8 neighbor rows ----
    {
        const int nl = tid >> 2, lane = tid & 3;   // 4 lanes/node, 16 fp8 each
        const int node = rowbase + nl;
        int beg = 0, end = 0;
        float d = 0.0f;
        if (node < N_NODES) { beg = row_beg[node]; end = row_end[node]; d = dinv[node]; }
        float a0[16] = {}, a1[16] = {};
        int j = beg;
        for (; j + 3 < end; j += 4) {
            uint4 v0 = *(const uint4*)(xq + (size_t)eidx[j] * 64 + lane * 16);
            uint4 v1 = *(const uint4*)(xq + (size_t)eidx[j + 1] * 64 + lane * 16);
            uint4 v2 = *(const uint4*)(xq + (size_t)eidx[j + 2] * 64 + lane * 16);
            uint4 v3 = *(const uint4*)(xq + (size_t)eidx[j + 3] * 64 + lane * 16);
            acc16(a0, v0); acc16(a1, v1); acc16(a0, v2); acc16(a1, v3);
        }
        for (; j < end; ++j) {
            uint4 v0 = *(const uint4*)(xq + (size_t)eidx[j] * 64 + lane * 16);
            acc16(a0, v0);
        }
        short8 o0, o1;
        #pragma unroll
        for (int i = 0; i < 8; ++i) {
            o0[i] = f2bf((a0[i] + a1[i]) * d);
            o1[i] = f2bf((a0[8 + i] + a1[8 + i]) * d);
        }
        *(short8*)(As + nl * AKP + lane * 16) = o0;
        *(short8*)(As + nl * AKP + lane * 16 + 8) = o1;
    }
    __syncthreads();

    const int w = tid >> 6, lane64 = tid & 63;
    const int ln = lane64 & 15, quad = lane64 >> 4;
    const int rwl = w * 16 + ln;
    int r = rowbase + rwl;
    if (r > N_NODES - 1) r = N_NODES - 1;

    float bias[4][4];
    #pragma unroll
    for (int ny = 0; ny < 4; ++ny)
        #pragma unroll
        for (int f = 0; f < 4; ++f)
            bias[ny][f] = b1[ny * 64 + f * 16 + ln];

    // ---- phase 1: gemm1, A = [As | xb]; per-ny h1 strip -> Bs -> h1g (coalesced) ----
    short8 a[4];
    a[0] = *(const short8*)(As + rwl * AKP + quad * 8);
    a[1] = *(const short8*)(As + rwl * AKP + 32 + quad * 8);
    a[2] = *(const short8*)(xb + (size_t)r * 64 + quad * 8);
    a[3] = *(const short8*)(xb + (size_t)r * 64 + 32 + quad * 8);
    short8 pb[4];
    #pragma unroll
    for (int i = 0; i < 4; ++i) {
        int idx = tid + i * 256, row = idx >> 4, off = (idx & 15) * 8;
        pb[i] = *(const short8*)(B1t + (size_t)row * K1 + off);
    }
    for (int ny = 0; ny < 4; ++ny) {
        lite_barrier();                    // Bs free (As / prev-strip reads drained)
        #pragma unroll
        for (int i = 0; i < 4; ++i) {
            int idx = tid + i * 256, row = idx >> 4, off = (idx & 15) * 8;
            *(short8*)(Bs + row * BKP + off) = pb[i];
        }
        if (ny < 3) {
            #pragma unroll
            for (int i = 0; i < 4; ++i) {
                int idx = tid + i * 256, row = idx >> 4, off = (idx & 15) * 8;
                pb[i] = *(const short8*)(B1t + (size_t)((ny + 1) * 64 + row) * K1 + off);
            }
        } else {                           // prefetch first phase-2 strip (ny2=0, kh=0)
            #pragma unroll
            for (int i = 0; i < 4; ++i) {
                int idx = tid + i * 256, row = idx >> 4, off = (idx & 15) * 8;
                pb[i] = *(const short8*)(B2t + (size_t)row * K2 + off);
            }
        }
        lite_barrier();                    // Bs ready; prefetch stays in flight
        floatx4 acc[4] = {};
        #pragma unroll
        for (int f = 0; f < 4; ++f) {
            const ushort_t* bp = Bs + (f * 16 + ln) * BKP + quad * 8;
            #pragma unroll
            for (int s = 0; s < 4; ++s) {
                short8 b = *(const short8*)(bp + s * 32);
                acc[f] = __builtin_amdgcn_mfma_f32_16x16x32_bf16(a[s], b, acc[f], 0, 0, 0);
            }
        }
        // h1 strip (relu+bias, bf16) -> Bs [64][AKP] -> coalesced h1g store
        lite_barrier();                    // B-strip reads done, Bs reusable
        #pragma unroll
        for (int f = 0; f < 4; ++f) {
            int nl0 = f * 16 + ln;
            #pragma unroll
            for (int g = 0; g < 4; ++g) {
                int rr = w * 16 + quad * 4 + g;
                Bs[rr * AKP + nl0] = f2bf(fmaxf(acc[f][g] + bias[ny][f], 0.0f));
            }
        }
        lite_barrier();                    // strip visible
        {
            int row2 = tid >> 2, seg = tid & 3;
            int gr = rowbase + row2;
            if (gr < N_NODES) {
                const uint4* s4 = (const uint4*)(Bs + row2 * AKP + seg * 16);
                uint4* d4 = (uint4*)(h1g + (size_t)gr * 256 + ny * 64 + seg * 16);
                d4[0] = s4[0]; d4[1] = s4[1];
            }
        }
    }
    __syncthreads();                       // full drain: all h1g stores visible to all waves

    // ---- phase 2: gemm2, A read back from h1g (L2-hot) ----
    short8 a2[8];
    #pragma unroll
    for (int s = 0; s < 8; ++s)
        a2[s] = *(const short8*)(h1g + (size_t)r * 256 + s * 32 + quad * 8);
    for (int ny = 0; ny < 4; ++ny) {
        floatx4 acc[4] = {};
        #pragma unroll
        for (int kh = 0; kh < 2; ++kh) {
            lite_barrier();                // Bs free (prev reads drained)
            #pragma unroll
            for (int i = 0; i < 4; ++i) {
                int idx = tid + i * 256, row = idx >> 4, off = (idx & 15) * 8;
                *(short8*)(Bs + row * BKP + off) = pb[i];
            }
            int st = ny * 2 + kh;
            if (st < 7) {
                int nyn = (st + 1) >> 1, khn = (st + 1) & 1;
                #pragma unroll
                for (int i = 0; i < 4; ++i) {
                    int idx = tid + i * 256, row = idx >> 4, off = (idx & 15) * 8;
                    pb[i] = *(const short8*)(B2t + (size_t)(nyn * 64 + row) * K2 + khn * 128 + off);
                }
            }
            lite_barrier();                // Bs ready
            #pragma unroll
            for (int f = 0; f < 4; ++f) {
                const ushort_t* bp = Bs + (f * 16 + ln) * BKP + quad * 8;
                #pragma unroll
                for (int s = 0; s < 4; ++s) {
                    short8 b = *(const short8*)(bp + s * 32);
                    acc[f] = __builtin_amdgcn_mfma_f32_16x16x32_bf16(a2[kh * 4 + s], b, acc[f], 0, 0, 0);
                }
            }
        }
        // per-ny output strip: ny 0-1 -> t2 (fp8), ny 2-3 -> r2 (bf16); staged via Bs
        lite_barrier();                    // B reads done
        if (ny < 2) {
            uchar_t* Ob = (uchar_t*)Bs;    // [64][80 B] fp8 strip (16B-aligned pitch)
            #pragma unroll
            for (int f = 0; f < 4; ++f) {
                int nl0 = f * 16 + ln;
                #pragma unroll
                for (int g = 0; g < 4; ++g) {
                    int rr = w * 16 + quad * 4 + g;
                    Ob[rr * 80 + nl0] = f2fp8(acc[f][g]);
                }
            }
            lite_barrier();
            int row2 = tid >> 2, seg = tid & 3;
            int gr = rowbase + row2;
            if (gr < N_NODES)
                *(uint4*)(t2 + (size_t)gr * 128 + ny * 64 + seg * 16) =
                    *(const uint4*)(Ob + row2 * 80 + seg * 16);
        } else {
            #pragma unroll
            for (int f = 0; f < 4; ++f) {
                int nl0 = f * 16 + ln;
                #pragma unroll
                for (int g = 0; g < 4; ++g) {
                    int rr = w * 16 + quad * 4 + g;
                    Bs[rr * AKP + nl0] = f2bf(acc[f][g]);
                }
            }
            lite_barrier();
            int row2 = tid >> 2, seg = tid & 3;
            int gr = rowbase + row2;
            if (gr < N_NODES) {
                const uint4* s4 = (const uint4*)(Bs + row2 * AKP + seg * 16);
                uint4* d4 = (uint4*)(r2 + (size_t)gr * 128 + (ny - 2) * 64 + seg * 16);
                d4[0] = s4[0]; d4[1] = s4[1];
            }
        }
    }
}

// ---------------- fused gather2 + combine + gemm3 (16 nodes/block, 16 threads/node) ----------------
__global__ __launch_bounds__(256) void g2g3_kernel(
    const uchar_t* __restrict__ t2, const ushort_t* __restrict__ r2,
    const int* __restrict__ row_beg, const int* __restrict__ row_end,
    const ushort_t* __restrict__ eidx, const float* __restrict__ dinv,
    const float* __restrict__ b2, const ushort_t* __restrict__ B3t,
    ushort_t* __restrict__ tml, float* __restrict__ rml) {
    constexpr int KP = 136;
    __shared__ ushort_t As[16 * KP];
    const int tid = threadIdx.x;
    const int nb = blockIdx.x * 16;   // 3125*16 = 50000 exact
    {
        const int nl = tid >> 4, lane = tid & 15;
        const int node = nb + nl;
        const int beg = row_beg[node], end = row_end[node];
        float a0[8] = {}, a1[8] = {}, a2[8] = {}, a3[8] = {};
        int j = beg;
        for (; j + 3 < end; j += 4) {
            uint2 v0 = *(const uint2*)(t2 + (size_t)eidx[j] * 128 + lane * 8);
            uint2 v1 = *(const uint2*)(t2 + (size_t)eidx[j + 1] * 128 + lane * 8);
            uint2 v2 = *(const uint2*)(t2 + (size_t)eidx[j + 2] * 128 + lane * 8);
            uint2 v3 = *(const uint2*)(t2 + (size_t)eidx[j + 3] * 128 + lane * 8);
            acc8(a0, v0); acc8(a1, v1); acc8(a2, v2); acc8(a3, v3);
        }
        for (; j < end; ++j) {
            uint2 v0 = *(const uint2*)(t2 + (size_t)eidx[j] * 128 + lane * 8);
            acc8(a0, v0);
        }
        float d = dinv[node];
        short8 rv = *(const short8*)(r2 + (size_t)node * 128 + lane * 8);
        float4 ba = ld4(b2 + lane * 8), bb = ld4(b2 + lane * 8 + 4);
        float bc[8] = {ba.x, ba.y, ba.z, ba.w, bb.x, bb.y, bb.z, bb.w};
        short8 o;
        #pragma unroll
        for (int i = 0; i < 8; ++i)
            o[i] = f2bf(fmaxf(((a0[i] + a1[i]) + (a2[i] + a3[i])) * d + bf2f((ushort_t)rv[i]) + bc[i], 0.0f));
        *(short8*)(As + nl * KP + lane * 8) = o;
    }
    __syncthreads();
    const int w = tid >> 6, lane64 = tid & 63;
    const int ln = lane64 & 15, quad = lane64 >> 4;
    short8 a[4];
    #pragma unroll
    for (int s = 0; s < 4; ++s)
        a[s] = *(const short8*)(As + ln * KP + s * 32 + quad * 8);
    floatx4 acc = {};
    const ushort_t* bp = B3t + (size_t)(w * 16 + ln) * 128 + quad * 8;
    #pragma unroll
    for (int s = 0; s < 4; ++s) {
        short8 b = *(const short8*)(bp + s * 32);
        acc = __builtin_amdgcn_mfma_f32_16x16x32_bf16(a[s], b, acc, 0, 0, 0);
    }
    const int r0 = nb + quad * 4;
    const int ncol = w * 16 + ln;
    #pragma unroll
    for (int g = 0; g < 4; ++g) {
        int rr = r0 + g;
        float v = acc[g];
        if (ncol < 32) tml[(size_t)rr * 32 + ncol] = f2bf(v);
        else rml[(size_t)rr * 32 + (ncol - 32)] = v;
    }
}

// ---------------- gather 3 (8 lanes/node, 32 nodes/block, fused combine + split write) ----
__global__ __launch_bounds__(256) void gather3_kernel(
    const ushort_t* __restrict__ tml, const float* __restrict__ rml,
    const int* __restrict__ row_beg, const int* __restrict__ row_end,
    const ushort_t* __restrict__ eidx, const float* __restrict__ dinv,
    const float* __restrict__ bmu, const float* __restrict__ bls,
    float* __restrict__ out) {
    const int lane = threadIdx.x & 7;          // 8 lanes/node, 4 bf16 each
    const int nl = threadIdx.x >> 3;
    const int n = blockIdx.x * 32 + nl;
    if (n >= N_NODES) return;
    const int beg = row_beg[n], end = row_end[n];
    float a0[4] = {}, a1[4] = {}, a2[4] = {}, a3[4] = {};
    int j = beg;
    for (; j + 3 < end; j += 4) {
        short4v v0 = *(const short4v*)(tml + (size_t)eidx[j] * 32 + lane * 4);
        short4v v1 = *(const short4v*)(tml + (size_t)eidx[j + 1] * 32 + lane * 4);
        short4v v2 = *(const short4v*)(tml + (size_t)eidx[j + 2] * 32 + lane * 4);
        short4v v3 = *(const short4v*)(tml + (size_t)eidx[j + 3] * 32 + lane * 4);
        #pragma unroll
        for (int i = 0; i < 4; ++i) {
            a0[i] += bf2f((ushort_t)v0[i]); a1[i] += bf2f((ushort_t)v1[i]);
            a2[i] += bf2f((ushort_t)v2[i]); a3[i] += bf2f((ushort_t)v3[i]);
        }
    }
    for (; j < end; ++j) {
        short4v v0 = *(const short4v*)(tml + (size_t)eidx[j] * 32 + lane * 4);
        #pragma unroll
        for (int i = 0; i < 4; ++i) a0[i] += bf2f((ushort_t)v0[i]);
    }
    float d = dinv[n];
    const float* bias = (lane < 4) ? (bmu + lane * 4) : (bls + (lane - 4) * 4);
    float4 ra = ld4(rml + (size_t)n * 32 + lane * 4);
    float4 ba = ld4(bias);
    float rr[4] = {ra.x, ra.y, ra.z, ra.w};
    float bc[4] = {ba.x, ba.y, ba.z, ba.w};
    float res[4];
    #pragma unroll
    for (int i = 0; i < 4; ++i) res[i] = ((a0[i] + a1[i]) + (a2[i] + a3[i])) * d + rr[i] + bc[i];
    float* base = (lane < 4) ? (out + (size_t)n * 16 + lane * 4)
                             : (out + 800000u + (size_t)n * 16 + (lane - 4) * 4);
    *(float4*)(base) = make_float4(res[0], res[1], res[2], res[3]);
}

extern "C" void kernel_launch(void* const* d_in, const int* in_sizes, int n_in,
                              void* d_out, int out_size, void* d_ws, size_t ws_size,
                              hipStream_t stream) {
    const float* x       = (const float*)d_in[0];
    const float* W1_rel  = (const float*)d_in[1];
    const float* b1      = (const float*)d_in[2];
    const float* W1_root = (const float*)d_in[3];
    const float* W2_rel  = (const float*)d_in[4];
    const float* b2      = (const float*)d_in[5];
    const float* W2_root = (const float*)d_in[6];
    const float* Wmu_rel = (const float*)d_in[7];
    const float* bmu     = (const float*)d_in[8];
    const float* Wmu_root= (const float*)d_in[9];
    const float* Wls_rel = (const float*)d_in[10];
    const float* bls     = (const float*)d_in[11];
    const float* Wls_root= (const float*)d_in[12];
    const int*   ei      = (const int*)d_in[13];
    const int* src = ei;
    const int* dst = ei + N_EDGES;

    // ---- workspace layout ----
    int*      bcursor = (int*)d_ws;                      //       256
    int*      row_beg = bcursor + 256;                   //    50,048
    int*      row_end = row_beg + 50048;                 //    50,048
    unsigned* pairbuf = (unsigned*)(row_end + 50048);    // 1,003,520
    ushort_t* eidx    = (ushort_t*)(pairbuf + 1003520);  // 1,003,520 ush
    float*    dinv    = (float*)(eidx + 1003520);        //    50,000
    ushort_t* xb   = (ushort_t*)(dinv + 50000);          //  3,200,000 ush [N,64] bf16
    uchar_t*  xq   = (uchar_t*)(xb + 3200000);           //  3,200,000 B   [N,64] fp8
    uchar_t*  t2   = xq + 3200000;                       //  6,400,000 B   [N,128] fp8
    ushort_t* r2   = (ushort_t*)(t2 + 6400000);          //  6,400,000 ush [N,128] bf16
    ushort_t* tml  = r2 + 6400000;                       //  1,600,000 ush [N,32]  bf16
    ushort_t* B1t  = tml + 1600000;                      //     32,768
    ushort_t* B2t  = B1t + 32768;                        //     65,536
    ushort_t* B3t  = B2t + 65536;                        //      8,192
    float* rml     = (float*)(B3t + 8192);               //  1,600,000 f32 [N,32]
    ushort_t* h1g  = (ushort_t*)(rml + 1600000);         // 12,800,000 ush [N,256] bf16 scratch
    float* out     = (float*)d_out;

    // ---- prep + CSR build ----
    prep_kernel<<<1980, 256, 0, stream>>>(x, W1_rel, W1_root, W2_rel, W2_root,
                                          Wmu_rel, Wls_rel, Wmu_root, Wls_root,
                                          xb, xq, B1t, B2t, B3t, bcursor);
    partition_kernel<<<PBLK, 512, 0, stream>>>(src, dst, bcursor, pairbuf);
    fill_bucket_kernel<<<NBUCK, 1024, 0, stream>>>(pairbuf, bcursor, row_beg, row_end, dinv, eidx);

    // ---- fused layer1 gather + gemm1 + gemm2 (one dispatch round) ----
    g1gemm12<<<782, 256, 0, stream>>>(xb, xq, row_beg, row_end, eidx, dinv,
                                      B1t, b1, B2t, h1g, t2, r2);

    // ---- layer 2 gather + fused layer-3 transform ----
    g2g3_kernel<<<3125, 256, 0, stream>>>(t2, r2, row_beg, row_end, eidx, dinv, b2, B3t, tml, rml);

    // ---- mu / logstd final aggregation ----
    gather3_kernel<<<1563, 256, 0, stream>>>(tml, rml, row_beg, row_end, eidx, dinv, bmu, bls, out);
}

// Round 11
// 190.272 us; speedup vs baseline: 1.0492x; 1.0130x over previous
//
#include <hip/hip_runtime.h>
#include <hip/hip_fp8.h>

#define N_NODES 50000
#define N_EDGES 800000
#define NBUCK 196       // ceil(50000/256) buckets of 256 nodes
#define PBLK 391        // ceil(800000/2048) partition blocks
#define CAP 5120        // bucket window capacity

typedef unsigned short ushort_t;
typedef unsigned char uchar_t;
typedef short short8 __attribute__((ext_vector_type(8)));
typedef short short4v __attribute__((ext_vector_type(4)));
typedef float floatx4 __attribute__((ext_vector_type(4)));
typedef float floatx2 __attribute__((ext_vector_type(2)));

__device__ __forceinline__ float bf2f(ushort_t u) {
    unsigned v = ((unsigned)u) << 16;
    return __builtin_bit_cast(float, v);
}
__device__ __forceinline__ ushort_t f2bf(float f) {
    unsigned u = __builtin_bit_cast(unsigned, f);
    unsigned r = (u + 0x7FFFu + ((u >> 16) & 1u)) >> 16;  // RNE
    return (ushort_t)r;
}
// HW OCP fp8 converts (gfx950)
__device__ __forceinline__ uchar_t f2fp8(float f) {
    return (uchar_t)(__builtin_amdgcn_cvt_pk_fp8_f32(f, f, 0, false) & 0xFF);
}
__device__ __forceinline__ float4 ld4(const float* p) { return *(const float4*)p; }

// LDS-only barrier: waits lgkm (ds ops) but leaves global loads/stores (vmcnt) in flight.
__device__ __forceinline__ void lite_barrier() {
    asm volatile("s_waitcnt lgkmcnt(0)" ::: "memory");
    __builtin_amdgcn_s_barrier();
}

__device__ __forceinline__ void acc16(float* a, uint4 v) {
    unsigned ws[4] = {v.x, v.y, v.z, v.w};
    #pragma unroll
    for (int wi = 0; wi < 4; ++wi) {
        floatx2 lo = __builtin_amdgcn_cvt_pk_f32_fp8(ws[wi], false);
        floatx2 hi = __builtin_amdgcn_cvt_pk_f32_fp8(ws[wi], true);
        a[wi * 4 + 0] += lo.x; a[wi * 4 + 1] += lo.y;
        a[wi * 4 + 2] += hi.x; a[wi * 4 + 3] += hi.y;
    }
}
__device__ __forceinline__ void acc8(float* a, uint2 v) {
    floatx2 p0 = __builtin_amdgcn_cvt_pk_f32_fp8(v.x, false);
    floatx2 p1 = __builtin_amdgcn_cvt_pk_f32_fp8(v.x, true);
    floatx2 p2 = __builtin_amdgcn_cvt_pk_f32_fp8(v.y, false);
    floatx2 p3 = __builtin_amdgcn_cvt_pk_f32_fp8(v.y, true);
    a[0] += p0.x; a[1] += p0.y; a[2] += p1.x; a[3] += p1.y;
    a[4] += p2.x; a[5] += p2.y; a[6] += p3.x; a[7] += p3.y;
}

// ---------------- prep: cvt_x (bf16 + fp8) + cvt_w + bucket cursor init ----------------
__global__ __launch_bounds__(256) void prep_kernel(
    const float* __restrict__ x,
    const float* __restrict__ W1_rel, const float* __restrict__ W1_root,
    const float* __restrict__ W2_rel, const float* __restrict__ W2_root,
    const float* __restrict__ Wmu_rel, const float* __restrict__ Wls_rel,
    const float* __restrict__ Wmu_root, const float* __restrict__ Wls_root,
    ushort_t* __restrict__ xb, uchar_t* __restrict__ xq,
    ushort_t* __restrict__ B1t, ushort_t* __restrict__ B2t, ushort_t* __restrict__ B3t,
    int* __restrict__ bcursor) {
    int idx = blockIdx.x * blockDim.x + threadIdx.x;
    if (idx < 400000) {                       // xb[n,:] = bf16(x); xq[n,:] = fp8(x)
        int n = idx >> 3, c = (idx & 7) * 8;
        float4 v0 = ld4(x + (size_t)n * 64 + c);
        float4 v1 = ld4(x + (size_t)n * 64 + c + 4);
        float vv[8] = {v0.x, v0.y, v0.z, v0.w, v1.x, v1.y, v1.z, v1.w};
        short8 o;
        #pragma unroll
        for (int i = 0; i < 8; ++i) o[i] = f2bf(vv[i]);
        int q0 = __builtin_amdgcn_cvt_pk_fp8_f32(vv[0], vv[1], 0, false);
        q0 = __builtin_amdgcn_cvt_pk_fp8_f32(vv[2], vv[3], q0, true);
        int q1 = __builtin_amdgcn_cvt_pk_fp8_f32(vv[4], vv[5], 0, false);
        q1 = __builtin_amdgcn_cvt_pk_fp8_f32(vv[6], vv[7], q1, true);
        *(short8*)(xb + (size_t)n * 64 + c) = o;
        uint2 q = {(unsigned)q0, (unsigned)q1};
        *(uint2*)(xq + (size_t)n * 64 + c) = q;
    } else if (idx < 506496) {                // transposed bf16 weights
        int j = idx - 400000;
        if (j < 32768) {
            int n = j >> 7, k = j & 127;
            float v = (k < 64) ? W1_rel[k * 256 + n] : W1_root[(k - 64) * 256 + n];
            B1t[j] = f2bf(v);
        } else if (j < 98304) {
            int jj = j - 32768;
            int n = jj >> 8, k = jj & 255;
            float v = (n < 128) ? W2_rel[k * 128 + n] : W2_root[k * 128 + (n - 128)];
            B2t[jj] = f2bf(v);
        } else {
            int jj = j - 98304;
            int n = jj >> 7, k = jj & 127;
            const float* W = (n < 16) ? Wmu_rel : (n < 32) ? Wls_rel : (n < 48) ? Wmu_root : Wls_root;
            B3t[jj] = f2bf(W[k * 16 + (n & 15)]);
        }
    } else if (idx < 506496 + NBUCK) {
        int b = idx - 506496;
        bcursor[b] = b * CAP;
    }
}

// ---------------- single-pass partition into fixed bucket windows (512 thr) ----------------
__global__ __launch_bounds__(512) void partition_kernel(
    const int* __restrict__ src, const int* __restrict__ dst,
    int* __restrict__ bcursor, unsigned* __restrict__ pairbuf) {
    __shared__ int h[NBUCK];
    __shared__ int cur[NBUCK];
    const int tid = threadIdx.x;
    for (int i = tid; i < NBUCK; i += 512) h[i] = 0;
    __syncthreads();
    const int base = blockIdx.x * 2048;
    int d[4];
    #pragma unroll
    for (int j = 0; j < 4; ++j) {
        int e = base + j * 512 + tid;
        if (e < N_EDGES) { d[j] = dst[e]; atomicAdd(&h[d[j] >> 8], 1); }
        else d[j] = -1;
    }
    __syncthreads();
    for (int i = tid; i < NBUCK; i += 512) {
        int c = h[i];
        cur[i] = c ? atomicAdd(&bcursor[i], c) : 0;
    }
    __syncthreads();
    #pragma unroll
    for (int j = 0; j < 4; ++j) {
        int e = base + j * 512 + tid;
        if (e < N_EDGES) {
            int dd = d[j];
            int slot = atomicAdd(&cur[dd >> 8], 1);
            pairbuf[slot] = (unsigned)src[e] | ((unsigned)(dd & 255) << 16);
        }
    }
}

// per-bucket (1024 thr): node histogram + scan -> row_beg/row_end/dinv; LDS-cursor eidx fill
__global__ __launch_bounds__(1024) void fill_bucket_kernel(
    const unsigned* __restrict__ pairbuf, const int* __restrict__ bcursor,
    int* __restrict__ row_beg, int* __restrict__ row_end,
    float* __restrict__ dinv, ushort_t* __restrict__ eidx) {
    __shared__ int h[256];
    __shared__ int sm[256];
    __shared__ int cur[256];
    const int b = blockIdx.x, tid = threadIdx.x;
    const int beg = b * CAP, end = bcursor[b];
    if (tid < 256) h[tid] = 0;
    __syncthreads();
    for (int i = beg + tid; i < end; i += 1024)
        atomicAdd(&h[pairbuf[i] >> 16], 1);
    __syncthreads();
    if (tid < 256) sm[tid] = h[tid];
    __syncthreads();
    #pragma unroll
    for (int off = 1; off < 256; off <<= 1) {
        int t = 0;
        if (tid < 256 && tid >= off) t = sm[tid - off];
        __syncthreads();
        if (tid < 256) sm[tid] += t;
        __syncthreads();
    }
    if (tid < 256) {
        int c = h[tid];
        int exc = beg + sm[tid] - c;
        int node = b * 256 + tid;
        if (node < N_NODES) {
            row_beg[node] = exc;
            row_end[node] = exc + c;
            dinv[node] = c > 0 ? 1.0f / (float)c : 0.0f;
        }
        cur[tid] = exc;
    }
    __syncthreads();
    for (int i = beg + tid; i < end; i += 1024) {
        unsigned v = pairbuf[i];
        int slot = atomicAdd(&cur[v >> 16], 1);
        eidx[slot] = (ushort_t)(v & 0xFFFFu);
    }
}

// ---------------- fused gather1 + gemm1 + gemm2 ----------------
// Double-buffered B strips (2 x 17.4 KB -> 4 blocks/CU, one dispatch round).
// Strip s+1 is ds-written to Bs[cur^1] WHILE MFMA consumes Bs[cur]; visibility via the
// next iteration's loop-top lite_barrier -> staging latency overlapped with MFMA+epilogue.
// Epilogue strips are XOR-swizzled (col ^= quad<<4) for conflict-free b16 scatter.
__global__ __launch_bounds__(256) void g1gemm12(
    const ushort_t* __restrict__ xb, const uchar_t* __restrict__ xq,
    const int* __restrict__ row_beg, const int* __restrict__ row_end,
    const ushort_t* __restrict__ eidx, const float* __restrict__ dinv,
    const ushort_t* __restrict__ B1t, const float* __restrict__ b1,
    const ushort_t* __restrict__ B2t, ushort_t* __restrict__ h1g,
    uchar_t* __restrict__ t2, ushort_t* __restrict__ r2) {
    constexpr int K1 = 128, K2 = 256;
    constexpr int AKP = 72;    // agg/out-strip pitch (64+8 ushorts, 144 B)
    constexpr int BKP = 136;   // B strip pitch (128+8)
    __shared__ ushort_t Bs[2][64 * BKP];   // 2 x 17.4 KB
    ushort_t* As = Bs[0];
    const int tid = threadIdx.x;
    const int rowbase = blockIdx.x * 64;

    // ---- phase 0: gather mean of fp8 neighbor rows ----
    {
        const int nl = tid >> 2, lane = tid & 3;   // 4 lanes/node, 16 fp8 each
        const int node = rowbase + nl;
        int beg = 0, end = 0;
        float d = 0.0f;
        if (node < N_NODES) { beg = row_beg[node]; end = row_end[node]; d = dinv[node]; }
        float a0[16] = {}, a1[16] = {};
        int j = beg;
        for (; j + 3 < end; j += 4) {
            uint4 v0 = *(const uint4*)(xq + (size_t)eidx[j] * 64 + lane * 16);
            uint4 v1 = *(const uint4*)(xq + (size_t)eidx[j + 1] * 64 + lane * 16);
            uint4 v2 = *(const uint4*)(xq + (size_t)eidx[j + 2] * 64 + lane * 16);
            uint4 v3 = *(const uint4*)(xq + (size_t)eidx[j + 3] * 64 + lane * 16);
            acc16(a0, v0); acc16(a1, v1); acc16(a0, v2); acc16(a1, v3);
        }
        for (; j < end; ++j) {
            uint4 v0 = *(const uint4*)(xq + (size_t)eidx[j] * 64 + lane * 16);
            acc16(a0, v0);
        }
        short8 o0, o1;
        #pragma unroll
        for (int i = 0; i < 8; ++i) {
            o0[i] = f2bf((a0[i] + a1[i]) * d);
            o1[i] = f2bf((a0[8 + i] + a1[8 + i]) * d);
        }
        *(short8*)(As + nl * AKP + lane * 16) = o0;
        *(short8*)(As + nl * AKP + lane * 16 + 8) = o1;
    }
    __syncthreads();

    const int w = tid >> 6, lane64 = tid & 63;
    const int ln = lane64 & 15, quad = lane64 >> 4;
    const int rwl = w * 16 + ln;
    int r = rowbase + rwl;
    if (r > N_NODES - 1) r = N_NODES - 1;

    float bias[4][4];
    #pragma unroll
    for (int ny = 0; ny < 4; ++ny)
        #pragma unroll
        for (int f = 0; f < 4; ++f)
            bias[ny][f] = b1[ny * 64 + f * 16 + ln];

    // A fragments
    short8 a[4];
    a[0] = *(const short8*)(As + rwl * AKP + quad * 8);
    a[1] = *(const short8*)(As + rwl * AKP + 32 + quad * 8);
    a[2] = *(const short8*)(xb + (size_t)r * 64 + quad * 8);
    a[3] = *(const short8*)(xb + (size_t)r * 64 + 32 + quad * 8);

    // strip source helper: strips 0-3 = B1t ny; strips 4-11 = B2t (ny2,kh)
    const int sb_row = tid >> 4;                 // rows 0..15 (+16i)
    const int sb_off = (tid & 15) * 8;
    #define STRIP_SRC(u, i) ((u) < 4 \
        ? (const short8*)(B1t + (size_t)((u) * 64 + sb_row + (i) * 16) * K1 + sb_off) \
        : (const short8*)(B2t + (size_t)((((u) - 4) >> 1) * 64 + sb_row + (i) * 16) * K2 + (((u) - 4) & 1) * 128 + sb_off))

    short8 pb[4];
    // prologue: prefetch strip 0, stage into Bs[1], prefetch strip 1
    #pragma unroll
    for (int i = 0; i < 4; ++i) pb[i] = *STRIP_SRC(0, i);
    #pragma unroll
    for (int i = 0; i < 4; ++i)
        *(short8*)(&Bs[1][(sb_row + i * 16) * BKP + sb_off]) = pb[i];
    #pragma unroll
    for (int i = 0; i < 4; ++i) pb[i] = *STRIP_SRC(1, i);
    lite_barrier();
    int cur = 1;

    // ---- phase 1: gemm1 over 4 strips ----
    for (int ny = 0; ny < 4; ++ny) {
        lite_barrier();                    // strip `cur` visible; Bs[cur^1] free
        #pragma unroll
        for (int i = 0; i < 4; ++i)
            *(short8*)(&Bs[cur ^ 1][(sb_row + i * 16) * BKP + sb_off]) = pb[i];
        {
            int u = ny + 2;                // strips 2..5 (always valid)
            #pragma unroll
            for (int i = 0; i < 4; ++i) pb[i] = *STRIP_SRC(u, i);
        }
        floatx4 acc[4] = {};
        #pragma unroll
        for (int f = 0; f < 4; ++f) {
            const ushort_t* bp = &Bs[cur][(f * 16 + ln) * BKP + quad * 8];
            #pragma unroll
            for (int s = 0; s < 4; ++s) {
                short8 b = *(const short8*)(bp + s * 32);
                acc[f] = __builtin_amdgcn_mfma_f32_16x16x32_bf16(a[s], b, acc[f], 0, 0, 0);
            }
        }
        lite_barrier();                    // all reads of Bs[cur] done -> reuse for h1 strip
        #pragma unroll
        for (int f = 0; f < 4; ++f) {
            int nl0 = (f * 16 + ln) ^ (quad << 4);   // XOR-swizzle: conflict-free b16 scatter
            #pragma unroll
            for (int g = 0; g < 4; ++g) {
                int rr = w * 16 + quad * 4 + g;
                Bs[cur][rr * AKP + nl0] = f2bf(fmaxf(acc[f][g] + bias[ny][f], 0.0f));
            }
        }
        lite_barrier();                    // strip visible
        {
            int row2 = tid >> 2, seg = tid & 3, q2 = (row2 >> 2) & 3;
            int gr = rowbase + row2;
            if (gr < N_NODES) {
                const uint4* s4 = (const uint4*)(&Bs[cur][row2 * AKP + ((seg ^ q2) << 4)]);
                uint4* d4 = (uint4*)(h1g + (size_t)gr * 256 + ny * 64 + seg * 16);
                d4[0] = s4[0]; d4[1] = s4[1];
            }
        }
        cur ^= 1;
    }
    __syncthreads();                       // drain: all h1g stores done (vmcnt) + block sync

    // ---- phase 2: gemm2, A from h1g (L2-hot), 8 strips in kh pairs ----
    short8 a2[8];
    #pragma unroll
    for (int s = 0; s < 8; ++s)
        a2[s] = *(const short8*)(h1g + (size_t)r * 256 + s * 32 + quad * 8);
    for (int ny2 = 0; ny2 < 4; ++ny2) {
        floatx4 acc[4] = {};
        #pragma unroll
        for (int kh = 0; kh < 2; ++kh) {
            int st = 4 + ny2 * 2 + kh;     // this strip (in Bs[cur])
            lite_barrier();                // strip cur visible; Bs[cur^1] free
            if (st < 11) {
                #pragma unroll
                for (int i = 0; i < 4; ++i)
                    *(short8*)(&Bs[cur ^ 1][(sb_row + i * 16) * BKP + sb_off]) = pb[i];
                if (st < 10) {
                    int u = st + 2;
                    #pragma unroll
                    for (int i = 0; i < 4; ++i) pb[i] = *STRIP_SRC(u, i);
                }
            }
            #pragma unroll
            for (int f = 0; f < 4; ++f) {
                const ushort_t* bp = &Bs[cur][(f * 16 + ln) * BKP + quad * 8];
                #pragma unroll
                for (int s = 0; s < 4; ++s) {
                    short8 b = *(const short8*)(bp + s * 32);
                    acc[f] = __builtin_amdgcn_mfma_f32_16x16x32_bf16(a2[kh * 4 + s], b, acc[f], 0, 0, 0);
                }
            }
            if (kh == 0) cur ^= 1;
        }
        // epilogue for this ny2 into the just-consumed buffer Bs[cur]
        lite_barrier();                    // all reads of Bs[cur] done
        if (ny2 < 2) {
            uchar_t* Ob = (uchar_t*)Bs[cur];   // [64][80 B] fp8 strip
            #pragma unroll
            for (int f = 0; f < 4; ++f) {
                int nl0 = (f * 16 + ln) ^ (quad << 4);
                #pragma unroll
                for (int g = 0; g < 4; ++g) {
                    int rr = w * 16 + quad * 4 + g;
                    Ob[rr * 80 + nl0] = f2fp8(acc[f][g]);
                }
            }
            lite_barrier();
            int row2 = tid >> 2, seg = tid & 3, q2 = (row2 >> 2) & 3;
            int gr = rowbase + row2;
            if (gr < N_NODES)
                *(uint4*)(t2 + (size_t)gr * 128 + ny2 * 64 + seg * 16) =
                    *(const uint4*)(Ob + row2 * 80 + ((seg ^ q2) << 4));
        } else {
            #pragma unroll
            for (int f = 0; f < 4; ++f) {
                int nl0 = (f * 16 + ln) ^ (quad << 4);
                #pragma unroll
                for (int g = 0; g < 4; ++g) {
                    int rr = w * 16 + quad * 4 + g;
                    Bs[cur][rr * AKP + nl0] = f2bf(acc[f][g]);
                }
            }
            lite_barrier();
            int row2 = tid >> 2, seg = tid & 3, q2 = (row2 >> 2) & 3;
            int gr = rowbase + row2;
            if (gr < N_NODES) {
                const uint4* s4 = (const uint4*)(&Bs[cur][row2 * AKP + ((seg ^ q2) << 4)]);
                uint4* d4 = (uint4*)(r2 + (size_t)gr * 128 + (ny2 - 2) * 64 + seg * 16);
                d4[0] = s4[0]; d4[1] = s4[1];
            }
        }
        cur ^= 1;
    }
    #undef STRIP_SRC
}

// ---------------- fused gather2 + combine + gemm3 (16 nodes/block, 16 threads/node) ----------------
__global__ __launch_bounds__(256) void g2g3_kernel(
    const uchar_t* __restrict__ t2, const ushort_t* __restrict__ r2,
    const int* __restrict__ row_beg, const int* __restrict__ row_end,
    const ushort_t* __restrict__ eidx, const float* __restrict__ dinv,
    const float* __restrict__ b2, const ushort_t* __restrict__ B3t,
    ushort_t* __restrict__ tml, float* __restrict__ rml) {
    constexpr int KP = 136;
    __shared__ ushort_t As[16 * KP];
    const int tid = threadIdx.x;
    const int nb = blockIdx.x * 16;   // 3125*16 = 50000 exact
    {
        const int nl = tid >> 4, lane = tid & 15;
        const int node = nb + nl;
        const int beg = row_beg[node], end = row_end[node];
        float a0[8] = {}, a1[8] = {}, a2[8] = {}, a3[8] = {};
        int j = beg;
        for (; j + 3 < end; j += 4) {
            uint2 v0 = *(const uint2*)(t2 + (size_t)eidx[j] * 128 + lane * 8);
            uint2 v1 = *(const uint2*)(t2 + (size_t)eidx[j + 1] * 128 + lane * 8);
            uint2 v2 = *(const uint2*)(t2 + (size_t)eidx[j + 2] * 128 + lane * 8);
            uint2 v3 = *(const uint2*)(t2 + (size_t)eidx[j + 3] * 128 + lane * 8);
            acc8(a0, v0); acc8(a1, v1); acc8(a2, v2); acc8(a3, v3);
        }
        for (; j < end; ++j) {
            uint2 v0 = *(const uint2*)(t2 + (size_t)eidx[j] * 128 + lane * 8);
            acc8(a0, v0);
        }
        float d = dinv[node];
        short8 rv = *(const short8*)(r2 + (size_t)node * 128 + lane * 8);
        float4 ba = ld4(b2 + lane * 8), bb = ld4(b2 + lane * 8 + 4);
        float bc[8] = {ba.x, ba.y, ba.z, ba.w, bb.x, bb.y, bb.z, bb.w};
        short8 o;
        #pragma unroll
        for (int i = 0; i < 8; ++i)
            o[i] = f2bf(fmaxf(((a0[i] + a1[i]) + (a2[i] + a3[i])) * d + bf2f((ushort_t)rv[i]) + bc[i], 0.0f));
        *(short8*)(As + nl * KP + lane * 8) = o;
    }
    __syncthreads();
    const int w = tid >> 6, lane64 = tid & 63;
    const int ln = lane64 & 15, quad = lane64 >> 4;
    short8 a[4];
    #pragma unroll
    for (int s = 0; s < 4; ++s)
        a[s] = *(const short8*)(As + ln * KP + s * 32 + quad * 8);
    floatx4 acc = {};
    const ushort_t* bp = B3t + (size_t)(w * 16 + ln) * 128 + quad * 8;
    #pragma unroll
    for (int s = 0; s < 4; ++s) {
        short8 b = *(const short8*)(bp + s * 32);
        acc = __builtin_amdgcn_mfma_f32_16x16x32_bf16(a[s], b, acc, 0, 0, 0);
    }
    const int r0 = nb + quad * 4;
    const int ncol = w * 16 + ln;
    #pragma unroll
    for (int g = 0; g < 4; ++g) {
        int rr = r0 + g;
        float v = acc[g];
        if (ncol < 32) tml[(size_t)rr * 32 + ncol] = f2bf(v);
        else rml[(size_t)rr * 32 + (ncol - 32)] = v;
    }
}

// ---------------- gather 3 (8 lanes/node, 32 nodes/block, fused combine + split write) ----
__global__ __launch_bounds__(256) void gather3_kernel(
    const ushort_t* __restrict__ tml, const float* __restrict__ rml,
    const int* __restrict__ row_beg, const int* __restrict__ row_end,
    const ushort_t* __restrict__ eidx, const float* __restrict__ dinv,
    const float* __restrict__ bmu, const float* __restrict__ bls,
    float* __restrict__ out) {
    const int lane = threadIdx.x & 7;          // 8 lanes/node, 4 bf16 each
    const int nl = threadIdx.x >> 3;
    const int n = blockIdx.x * 32 + nl;
    if (n >= N_NODES) return;
    const int beg = row_beg[n], end = row_end[n];
    float a0[4] = {}, a1[4] = {}, a2[4] = {}, a3[4] = {};
    int j = beg;
    for (; j + 3 < end; j += 4) {
        short4v v0 = *(const short4v*)(tml + (size_t)eidx[j] * 32 + lane * 4);
        short4v v1 = *(const short4v*)(tml + (size_t)eidx[j + 1] * 32 + lane * 4);
        short4v v2 = *(const short4v*)(tml + (size_t)eidx[j + 2] * 32 + lane * 4);
        short4v v3 = *(const short4v*)(tml + (size_t)eidx[j + 3] * 32 + lane * 4);
        #pragma unroll
        for (int i = 0; i < 4; ++i) {
            a0[i] += bf2f((ushort_t)v0[i]); a1[i] += bf2f((ushort_t)v1[i]);
            a2[i] += bf2f((ushort_t)v2[i]); a3[i] += bf2f((ushort_t)v3[i]);
        }
    }
    for (; j < end; ++j) {
        short4v v0 = *(const short4v*)(tml + (size_t)eidx[j] * 32 + lane * 4);
        #pragma unroll
        for (int i = 0; i < 4; ++i) a0[i] += bf2f((ushort_t)v0[i]);
    }
    float d = dinv[n];
    const float* bias = (lane < 4) ? (bmu + lane * 4) : (bls + (lane - 4) * 4);
    float4 ra = ld4(rml + (size_t)n * 32 + lane * 4);
    float4 ba = ld4(bias);
    float rr[4] = {ra.x, ra.y, ra.z, ra.w};
    float bc[4] = {ba.x, ba.y, ba.z, ba.w};
    float res[4];
    #pragma unroll
    for (int i = 0; i < 4; ++i) res[i] = ((a0[i] + a1[i]) + (a2[i] + a3[i])) * d + rr[i] + bc[i];
    float* base = (lane < 4) ? (out + (size_t)n * 16 + lane * 4)
                             : (out + 800000u + (size_t)n * 16 + (lane - 4) * 4);
    *(float4*)(base) = make_float4(res[0], res[1], res[2], res[3]);
}

extern "C" void kernel_launch(void* const* d_in, const int* in_sizes, int n_in,
                              void* d_out, int out_size, void* d_ws, size_t ws_size,
                              hipStream_t stream) {
    const float* x       = (const float*)d_in[0];
    const float* W1_rel  = (const float*)d_in[1];
    const float* b1      = (const float*)d_in[2];
    const float* W1_root = (const float*)d_in[3];
    const float* W2_rel  = (const float*)d_in[4];
    const float* b2      = (const float*)d_in[5];
    const float* W2_root = (const float*)d_in[6];
    const float* Wmu_rel = (const float*)d_in[7];
    const float* bmu     = (const float*)d_in[8];
    const float* Wmu_root= (const float*)d_in[9];
    const float* Wls_rel = (const float*)d_in[10];
    const float* bls     = (const float*)d_in[11];
    const float* Wls_root= (const float*)d_in[12];
    const int*   ei      = (const int*)d_in[13];
    const int* src = ei;
    const int* dst = ei + N_EDGES;

    // ---- workspace layout ----
    int*      bcursor = (int*)d_ws;                      //       256
    int*      row_beg = bcursor + 256;                   //    50,048
    int*      row_end = row_beg + 50048;                 //    50,048
    unsigned* pairbuf = (unsigned*)(row_end + 50048);    // 1,003,520
    ushort_t* eidx    = (ushort_t*)(pairbuf + 1003520);  // 1,003,520 ush
    float*    dinv    = (float*)(eidx + 1003520);        //    50,000
    ushort_t* xb   = (ushort_t*)(dinv + 50000);          //  3,200,000 ush [N,64] bf16
    uchar_t*  xq   = (uchar_t*)(xb + 3200000);           //  3,200,000 B   [N,64] fp8
    uchar_t*  t2   = xq + 3200000;                       //  6,400,000 B   [N,128] fp8
    ushort_t* r2   = (ushort_t*)(t2 + 6400000);          //  6,400,000 ush [N,128] bf16
    ushort_t* tml  = r2 + 6400000;                       //  1,600,000 ush [N,32]  bf16
    ushort_t* B1t  = tml + 1600000;                      //     32,768
    ushort_t* B2t  = B1t + 32768;                        //     65,536
    ushort_t* B3t  = B2t + 65536;                        //      8,192
    float* rml     = (float*)(B3t + 8192);               //  1,600,000 f32 [N,32]
    ushort_t* h1g  = (ushort_t*)(rml + 1600000);         // 12,800,000 ush [N,256] bf16 scratch
    float* out     = (float*)d_out;

    // ---- prep + CSR build ----
    prep_kernel<<<1980, 256, 0, stream>>>(x, W1_rel, W1_root, W2_rel, W2_root,
                                          Wmu_rel, Wls_rel, Wmu_root, Wls_root,
                                          xb, xq, B1t, B2t, B3t, bcursor);
    partition_kernel<<<PBLK, 512, 0, stream>>>(src, dst, bcursor, pairbuf);
    fill_bucket_kernel<<<NBUCK, 1024, 0, stream>>>(pairbuf, bcursor, row_beg, row_end, dinv, eidx);

    // ---- fused layer1 gather + gemm1 + gemm2 (dbuf strips, one dispatch round) ----
    g1gemm12<<<782, 256, 0, stream>>>(xb, xq, row_beg, row_end, eidx, dinv,
                                      B1t, b1, B2t, h1g, t2, r2);

    // ---- layer 2 gather + fused layer-3 transform ----
    g2g3_kernel<<<3125, 256, 0, stream>>>(t2, r2, row_beg, row_end, eidx, dinv, b2, B3t, tml, rml);

    // ---- mu / logstd final aggregation ----
    gather3_kernel<<<1563, 256, 0, stream>>>(tml, rml, row_beg, row_end, eidx, dinv, bmu, bls, out);
}